// Round 15
// baseline (699.430 us; speedup 1.0000x reference)
//
#include <hip/hip_runtime.h>
#include <cmath>
#include <vector>
#include <algorithm>

// ---------------- constant table offsets (in floats) ----------------
enum : int {
  OFF_WIN  = 0,
  OFF_WL1  = 128,
  OFF_WL2  = 160,
  OFF_DCOL = 176,                  // 256*128
  OFF_D1A  = OFF_DCOL + 32768,     // 174592: (2l+1)*d, layout [(o3+idx)*32 + k]
  OFF_D1B  = OFF_D1A + 174592,     // 174592: 2pi*wl1[k]*d/1024, layout [(o3+idx)*32 + k]
  OFF_D2   = OFF_D1B + 174592,     // 10880: (2l+1)*d2, layout [(o3+idx)*16 + k2]
  OFF_PSI2 = OFF_D2 + 10880,       // 12288
  OFF_PSI3 = OFF_PSI2 + 12288,     // 261120
  CONST_TOTAL = OFF_PSI3 + 261120
};

// ---------------- workspace layout (bytes) ----------------
static constexpr size_t OFS_XF1  = 0;
static constexpr size_t OFS_FX   = 507904;
static constexpr size_t OFS_FY1  = 540672;
static constexpr size_t OFS_FX2  = 671744;     // bf16 A-hat
static constexpr size_t OFS_FY2  = 6242304;    // bf16 B-hat
static constexpr size_t OFS_FZ2  = 50806784;   // 680*2048 c64
static constexpr size_t OFS_W2T  = OFS_FZ2;    // w2t overlaps Fz2
static constexpr size_t OFS_FEAT = 61947904;
static constexpr size_t WS_NEEDED = 61956096;

static inline int off3h(int l){ return (4*l*l*l - l)/3; }

// ---------------- host-side constant construction ----------------
namespace {

double fact_[32];
void init_fact(){ fact_[0]=1.0; for(int i=1;i<32;i++) fact_[i]=fact_[i-1]*i; }

void wigner_d(int l, double beta, double* d){
  int n = 2*l+1;
  double cb = std::cos(beta*0.5), sb = std::sin(beta*0.5);
  for(int r=0;r<n;r++){ int mp = r-l;
    for(int c=0;c<n;c++){ int m = c-l;
      double f = std::sqrt(fact_[l+mp]*fact_[l-mp]*fact_[l+m]*fact_[l-m]);
      int s0 = std::max(0, m-mp), s1 = std::min(l+m, l-mp);
      double sum = 0;
      for(int s=s0;s<=s1;s++){
        double t = (((mp-m+s)&1)? -1.0 : 1.0)
                 / (fact_[l+m-s]*fact_[s]*fact_[mp-m+s]*fact_[l-mp-s]);
        t *= std::pow(cb, (double)(2*l+m-mp-2*s)) * std::pow(sb, (double)(mp-m+2*s));
        sum += t;
      }
      d[r*n+c] = f*sum;
    }
  }
}

void dh_weights(int b, double* w){
  for(int j=0;j<2*b;j++){
    double s = 0;
    for(int l=0;l<b;l++) s += std::sin((2.0*j+1)*(2.0*l+1)*M_PI/(4.0*b))/(2.0*l+1);
    w[j] = (2.0/b)*std::sin(M_PI*(2.0*j+1)/(4.0*b))*s;
  }
}

float* g_const = nullptr;

struct ConstInit {
  ConstInit(){
    init_fact();
    std::vector<float> h((size_t)CONST_TOTAL, 0.0f);
    std::vector<double> tmp(31*31);
    std::vector<double> wl1(32);
    { std::vector<double> w(128); dh_weights(64, w.data()); for(int i=0;i<128;i++) h[OFF_WIN+i]=(float)w[i]; }
    { dh_weights(16, wl1.data()); for(int i=0;i<32;i++)  h[OFF_WL1+i]=(float)wl1[i]; }
    { std::vector<double> w(16);  dh_weights(8,  w.data()); for(int i=0;i<16;i++)  h[OFF_WL2+i]=(float)w[i]; }
    for(int l=0;l<16;l++){ int n=2*l+1;
      for(int k=0;k<128;k++){
        wigner_d(l, M_PI*(2.0*k+1)/256.0, tmp.data());
        for(int mi=0;mi<n;mi++) h[OFF_DCOL + (size_t)(l*l+mi)*128 + k] = (float)tmp[mi*n + l];
      }
    }
    for(int l=0;l<16;l++){ int n=2*l+1;
      for(int k=0;k<32;k++){
        wigner_d(l, M_PI*(2.0*k+1)/64.0, tmp.data());
        for(int t=0;t<n*n;t++){
          size_t base = (size_t)(off3h(l)+t)*32 + k;
          h[OFF_D1A + base] = (float)((2*l+1)*tmp[t]);
          if(l < 8)
            h[OFF_D1B + base] = (float)(2.0*M_PI*wl1[k]*tmp[t]/1024.0);
        }
      }
    }
    for(int l=0;l<8;l++){ int n=2*l+1;
      for(int k=0;k<16;k++){
        wigner_d(l, M_PI*(2.0*k+1)/32.0, tmp.data());
        for(int t=0;t<n*n;t++)
          h[OFF_D2 + (size_t)(off3h(l)+t)*16 + k] = (float)((2*l+1)*tmp[t]);
      }
    }
    for(int l=0;l<16;l++){ int n=2*l+1;
      for(int i=0;i<3;i++){
        wigner_d(l, (i+1)*(M_PI/8.0)/3.0, tmp.data());
        for(int j=0;j<8;j++){
          double alpha = 2.0*M_PI*j/8.0;
          int g = i*8+j;
          for(int mi=0;mi<n;mi++){
            double d = tmp[mi*n + l];
            double th = (double)(mi-l)*alpha;
            size_t base = OFF_PSI2 + ((size_t)(l*l+mi)*24 + g)*2;
            h[base+0] = (float)( d*std::cos(th));
            h[base+1] = (float)(-d*std::sin(th));
          }
        }
      }
    }
    for(int l=0;l<8;l++){ int n=2*l+1;
      for(int i=0;i<3;i++){
        wigner_d(l, (i+1)*(M_PI/8.0)/3.0, tmp.data());
        for(int j=0;j<8;j++){
          double alpha = 2.0*M_PI*j/8.0;
          for(int kk=0;kk<8;kk++){
            double gamma = 2.0*M_PI*kk/8.0 - alpha;
            int g = (i*8+j)*8+kk;
            for(int mi=0;mi<n;mi++) for(int ni=0;ni<n;ni++){
              double d = tmp[mi*n+ni];
              double th = (double)(mi-l)*alpha + (double)(ni-l)*gamma;
              size_t base = OFF_PSI3 + (((size_t)off3h(l)+ (size_t)mi*n+ni)*192 + g)*2;
              h[base+0] = (float)( d*std::cos(th));
              h[base+1] = (float)(-d*std::sin(th));
            }
          }
        }
      }
    }
    hipMalloc((void**)&g_const, sizeof(float)*(size_t)CONST_TOTAL);
    hipMemcpy(g_const, h.data(), sizeof(float)*(size_t)CONST_TOTAL, hipMemcpyHostToDevice);
  }
};
ConstInit g_init_;

} // namespace

// ---------------- device helpers ----------------
__device__ __forceinline__ int off3d(int l){ return (4*l*l*l - l)/3; }
constexpr float TWO_PI_F = 6.28318530717958647692f;

__device__ __forceinline__ unsigned int f2bf(float f){
  union { float f; unsigned int u; } v; v.f = f;
  unsigned int r = v.u + 0x7FFFu + ((v.u >> 16) & 1u);
  return r >> 16;
}
__device__ __forceinline__ unsigned int pk2(float2 v){
  return f2bf(v.x) | (f2bf(v.y) << 16);
}
__device__ __forceinline__ float bflo(unsigned int u){
  union { unsigned int u; float f; } c; c.u = u << 16; return c.f;
}
__device__ __forceinline__ float bfhi(unsigned int u){
  union { unsigned int u; float f; } c; c.u = u & 0xffff0000u; return c.f;
}
// intra-wave LDS ordering: compiler fence + full waitcnt drain (scalar op)
__device__ __forceinline__ void wave_fence(){
  __asm__ volatile("" ::: "memory");
  __builtin_amdgcn_s_waitcnt(0);
  __asm__ volatile("" ::: "memory");
}

typedef __attribute__((ext_vector_type(8))) short bf16x8;
typedef __attribute__((ext_vector_type(4))) float f32x4;

// K1: xf1[b,k,m] — 4-way a-split + LDS reduce
__global__ void k_fft_alpha(const float* __restrict__ x, float2* __restrict__ xf1){
  __shared__ float row[128];
  __shared__ float2 w128[128];
  __shared__ float2 red2[4][31];
  int r = blockIdx.x;
  int t = threadIdx.x;
  row[t] = x[(size_t)r*128 + t];
  float ang = (TWO_PI_F/128.0f)*t;
  w128[t] = make_float2(cosf(ang), sinf(ang));
  __syncthreads();
  int mi = t & 31, part = t >> 5;
  if(mi < 31){
    int m = mi - 15;
    float2 acc = make_float2(0.f,0.f);
    int a0 = part*32;
    for(int a=a0;a<a0+32;a++){
      float2 w = w128[(m*a)&127];
      acc.x += row[a]*w.x;
      acc.y -= row[a]*w.y;
    }
    red2[part][mi] = acc;
  }
  __syncthreads();
  if(t < 31){
    float2 s = red2[0][t];
    float2 s1 = red2[1][t], s2 = red2[2][t], s3 = red2[3][t];
    s.x += s1.x + s2.x + s3.x;
    s.y += s1.y + s2.y + s3.y;
    xf1[(size_t)r*31 + t] = s;
  }
}

// K2: Fx[c2][b] — 4-way k-split, LDS reduce
__global__ void k_fx(const float* __restrict__ cst, const float2* __restrict__ xf1,
                     float2* __restrict__ FxP){
  __shared__ float2 redL[256];
  int lp = threadIdx.x & 63;
  int kc = threadIdx.x >> 6;
  int idx = blockIdx.x*64 + lp;
  int c2 = idx >> 4, b = idx & 15;
  int l = 0; while((l+1)*(l+1) <= c2) l++;
  int m = (c2 - l*l) - l;
  const float* W  = cst + OFF_WIN;
  const float* DC = cst + OFF_DCOL + (size_t)c2*128;
  float2 acc = make_float2(0.f,0.f);
  int k0 = kc*32;
  for(int k=k0;k<k0+32;k++){
    float wv = W[k]*DC[k];
    float2 xv = xf1[((size_t)b*128+k)*31 + (m+15)];
    acc.x += wv*xv.x; acc.y += wv*xv.y;
  }
  redL[threadIdx.x] = acc;
  __syncthreads();
  if(kc == 0){
    float2 p1 = redL[lp+64], p2 = redL[lp+128], p3 = redL[lp+192];
    acc.x += p1.x + p2.x + p3.x;
    acc.y += p1.y + p2.y + p3.y;
    float s = TWO_PI_F/128.0f;
    FxP[(size_t)c2*16+b] = make_float2(acc.x*s, acc.y*s);
  }
}

// K3: Fy1[c2][o]
__global__ void k_fy1(const float* __restrict__ cst, const float* __restrict__ w1,
                      float2* __restrict__ FyP){
  int idx = blockIdx.x*blockDim.x + threadIdx.x;
  int c2 = idx >> 6, o = idx & 63;
  const float2* psi = (const float2*)(cst + OFF_PSI2) + (size_t)c2*24;
  const float* w1r = w1 + (size_t)o*24;
  float2 acc = make_float2(0.f,0.f);
  for(int g=0;g<24;g++){
    float wv = w1r[g];
    float2 p = psi[g];
    acc.x += wv*p.x; acc.y += wv*p.y;
  }
  FyP[(size_t)c2*64+o] = acc;
}

// K4: fused first conv — KT=4, Hermitian-halved, bank-uniform cells, bf16 T/y LDS.
// stage5+accum merged: 120 threads each accumulate (mp,np) AND the Hermitian
// mirror (-mp,-np) directly -> 5 barriers/kt (was 6), no XfB round-trip.
__global__ void __launch_bounds__(256,4) k_conv1(const float* __restrict__ cst,
                                                 const float2* __restrict__ FxP,
                                                 const float2* __restrict__ FyP,
                                                 unsigned int* __restrict__ FxB){
  __shared__ __align__(16) char L[39936];
  float2* FxL = (float2*)L;
  float2* FyL = FxL + 256;
  float2* SB  = (float2*)(L + 4096);
  unsigned int* yBu = (unsigned int*)(L + 4096);
  unsigned int* TBu = (unsigned int*)(L + 23936);
  float2* T2B = (float2*)(L + 23936);
  float2* acc2= (float2*)(L + 34176);
  float2* w32 = (float2*)(L + 39616);
  int*    o3T = (int*)(L + 39872);

  int b = blockIdx.x >> 6, o = blockIdx.x & 63;
  int tid = threadIdx.x;
  if(tid < 32){ float ang = (TWO_PI_F/32.0f)*tid; w32[tid] = make_float2(cosf(ang), sinf(ang)); }
  if(tid < 16){ int l = tid; o3T[l] = (4*l*l*l - l)/3; }
  FxL[tid] = FxP[(size_t)tid*16 + b];
  FyL[tid] = FyP[(size_t)tid*64 + o];
  for(int t=tid; t<680; t+=256) acc2[t] = make_float2(0.f,0.f);

  const float* D1A = cst + OFF_D1A;
  const float* D1B = cst + OFF_D1B;

  for(int kt=0; kt<8; kt++){
    int k0 = kt*4;
    __syncthreads();
    for(int t=tid; t<496; t+=256){
      int mi = t/31, niq = t - mi*31;
      int n = niq-15;
      int an = n<0?-n:n;
      int lmin = mi>an?mi:an;
      float2 s0={0,0},s1={0,0},s2={0,0},s3={0,0};
      for(int l=lmin;l<16;l++){
        int c = 2*l+1, l2 = l*l;
        float2 fx = FxL[l2+l+mi];
        float2 fy = FyL[l2+(n+l)];
        float zx = fx.x*fy.x + fx.y*fy.y;
        float zy = fx.y*fy.x - fx.x*fy.y;
        const float4* dp = (const float4*)(D1A + (((size_t)o3T[l] + (mi+l)*c + (n+l))<<5) + k0);
        float4 d0 = dp[0];
        s0.x += d0.x*zx; s0.y += d0.x*zy;
        s1.x += d0.y*zx; s1.y += d0.y*zy;
        s2.x += d0.z*zx; s2.y += d0.z*zy;
        s3.x += d0.w*zx; s3.y += d0.w*zy;
      }
      float2* sp = SB + (size_t)t*5;
      sp[0]=s0; sp[1]=s1; sp[2]=s2; sp[3]=s3;
    }
    __syncthreads();
    {
      int mi = tid >> 4, cp = tid & 15;
      float2 a0[4], a1[4];
      #pragma unroll
      for(int j=0;j<4;j++){ a0[j]=make_float2(0,0); a1[j]=make_float2(0,0); }
      float2 step = w32[cp];
      float2 wv = w32[(15*cp)&31];
      float2 cur = make_float2(wv.x, -wv.y);
      const float2* srow = SB + (size_t)(mi*31)*5;
      for(int nb=0; nb<31; nb++){
        float2 q0 = srow[nb*5+0], q1 = srow[nb*5+1], q2 = srow[nb*5+2], q3 = srow[nb*5+3];
        float px, py;
        bool odd = (nb & 1);
        #define K1STEP(QX,QY,J) \
          px = QX*cur.x - QY*cur.y; py = QX*cur.y + QY*cur.x; \
          a0[J].x += px; a0[J].y += py; \
          if(odd){ a1[J].x += px; a1[J].y += py; } else { a1[J].x -= px; a1[J].y -= py; }
        K1STEP(q0.x,q0.y,0) K1STEP(q1.x,q1.y,1)
        K1STEP(q2.x,q2.y,2) K1STEP(q3.x,q3.y,3)
        #undef K1STEP
        float nx = cur.x*step.x - cur.y*step.y;
        cur.y = cur.x*step.y + cur.y*step.x;
        cur.x = nx;
      }
      unsigned int* tp0 = TBu + (size_t)(mi*32+cp)*5;
      tp0[0]=pk2(a0[0]); tp0[1]=pk2(a0[1]); tp0[2]=pk2(a0[2]); tp0[3]=pk2(a0[3]);
      unsigned int* tp1 = TBu + (size_t)(mi*32+cp+16)*5;
      tp1[0]=pk2(a1[0]); tp1[1]=pk2(a1[1]); tp1[2]=pk2(a1[2]); tp1[3]=pk2(a1[3]);
    }
    __syncthreads();
    {
      int c = tid & 31, aq = tid >> 5;
      float y0[4],y1[4],y2[4],y3[4], t0x[4];
      {
        const unsigned int* t0p = TBu + (size_t)c*5;
        t0x[0]=bflo(t0p[0]); t0x[1]=bflo(t0p[1]); t0x[2]=bflo(t0p[2]); t0x[3]=bflo(t0p[3]);
      }
      #pragma unroll
      for(int j=0;j<4;j++){ y0[j]=0; y1[j]=0; y2[j]=0; y3[j]=0; }
      #pragma unroll
      for(int m=1;m<16;m++){
        float2 w = w32[(m*aq)&31];
        const unsigned int* tp = TBu + (size_t)(m*32+c)*5;
        unsigned int d0=tp[0], d1=tp[1], d2=tp[2], d3=tp[3];
        float tx[4] = {bflo(d0),bflo(d1),bflo(d2),bflo(d3)};
        float ty[4] = {bfhi(d0),bfhi(d1),bfhi(d2),bfhi(d3)};
        #pragma unroll
        for(int j=0;j<4;j++){
          float px = tx[j]*w.x - ty[j]*w.y;
          float py = tx[j]*w.y + ty[j]*w.x;
          y0[j] += px;
          int r = m & 3;
          if(r==0){ y1[j] += px; y3[j] += px; }
          else if(r==1){ y1[j] -= py; y3[j] += py; }
          else if(r==2){ y1[j] -= px; y3[j] -= px; }
          else { y1[j] += py; y3[j] -= py; }
          y2[j] += (m&1)? -px : px;
        }
      }
      #define YWRITE(A, YV) { \
        float v0 = t0x[0]+2.f*YV[0], v1 = t0x[1]+2.f*YV[1], v2 = t0x[2]+2.f*YV[2], v3 = t0x[3]+2.f*YV[3]; \
        v0 = v0>0?v0:0; v1 = v1>0?v1:0; v2 = v2>0?v2:0; v3 = v3>0?v3:0; \
        unsigned int* yp = yBu + ((size_t)(A)*32 + c)*3; \
        yp[0] = f2bf(v0) | (f2bf(v1)<<16); \
        yp[1] = f2bf(v2) | (f2bf(v3)<<16); }
      YWRITE(aq,    y0)
      YWRITE(aq+8,  y1)
      YWRITE(aq+16, y2)
      YWRITE(aq+24, y3)
      #undef YWRITE
    }
    __syncthreads();
    {
      int mp = tid >> 5, c4 = tid & 31;
      float2 t2[4];
      #pragma unroll
      for(int j=0;j<4;j++) t2[j]=make_float2(0,0);
      for(int a=0;a<32;a++){
        float2 w = w32[(mp*a)&31];
        const unsigned int* yp = yBu + ((size_t)a*32 + c4)*3;
        unsigned int d0 = yp[0], d1 = yp[1];
        float yv[4] = {bflo(d0), bfhi(d0), bflo(d1), bfhi(d1)};
        #pragma unroll
        for(int j=0;j<4;j++){
          t2[j].x += yv[j]*w.x;
          t2[j].y -= yv[j]*w.y;
        }
      }
      float2* tp = T2B + (size_t)(mp*32+c4)*5;
      tp[0]=t2[0]; tp[1]=t2[1]; tp[2]=t2[2]; tp[3]=t2[3];
    }
    __syncthreads();
    // ---- stage5 + accum merged ----
    if(tid < 120){
      int mp = tid/15, npq = tid - mp*15;
      int np = npq-7;
      float2 xf0={0,0}, xf1v={0,0}, xf2={0,0}, xf3={0,0};
      float2 wv = w32[np&31];
      float2 step = make_float2(wv.x, -wv.y);
      float2 cur = make_float2(1.f, 0.f);
      const float2* trow = T2B + (size_t)(mp*32)*5;
      for(int c=0;c<32;c++){
        float2 q0 = trow[c*5+0], q1 = trow[c*5+1], q2 = trow[c*5+2], q3 = trow[c*5+3];
        xf0.x  += q0.x*cur.x - q0.y*cur.y;  xf0.y  += q0.x*cur.y + q0.y*cur.x;
        xf1v.x += q1.x*cur.x - q1.y*cur.y;  xf1v.y += q1.x*cur.y + q1.y*cur.x;
        xf2.x  += q2.x*cur.x - q2.y*cur.y;  xf2.y  += q2.x*cur.y + q2.y*cur.x;
        xf3.x  += q3.x*cur.x - q3.y*cur.y;  xf3.y  += q3.x*cur.y + q3.y*cur.x;
        float nx = cur.x*step.x - cur.y*step.y;
        cur.y = cur.x*step.y + cur.y*step.x;
        cur.x = nx;
      }
      int an = np<0?-np:np;
      int lmin = mp>an?mp:an;
      for(int l=lmin;l<8;l++){
        int c2 = 2*l+1;
        int cidx = o3T[l] + (mp+l)*c2 + (np+l);
        const float4* dp = (const float4*)(D1B + (((size_t)cidx)<<5) + k0);
        float4 d0 = dp[0];
        float rx = d0.x*xf0.x + d0.y*xf1v.x + d0.z*xf2.x + d0.w*xf3.x;
        float ry = d0.x*xf0.y + d0.y*xf1v.y + d0.z*xf2.y + d0.w*xf3.y;
        float2 cu = acc2[cidx];
        cu.x += rx; cu.y += ry;
        acc2[cidx] = cu;
        if(mp > 0){
          int cidx2 = o3T[l] + (l-mp)*c2 + (l-np);
          const float4* dp2 = (const float4*)(D1B + (((size_t)cidx2)<<5) + k0);
          float4 d2 = dp2[0];
          float rx2 = d2.x*xf0.x + d2.y*xf1v.x + d2.z*xf2.x + d2.w*xf3.x;
          float ry2 = -(d2.x*xf0.y + d2.y*xf1v.y + d2.z*xf2.y + d2.w*xf3.y);
          float2 cu2 = acc2[cidx2];
          cu2.x += rx2; cu2.y += ry2;
          acc2[cidx2] = cu2;
        }
      }
    }
  }
  __syncthreads();
  for(int t=tid; t<680; t+=256){
    float2 v = acc2[t];
    unsigned int pk = f2bf(v.x) | (f2bf(v.y) << 16);
    FxB[(size_t)t*1024 + b*64 + o] = pk;
  }
}

// K5: transpose w2 [i*128+o][192g] -> w2t [g][o*64+i]
__global__ void k_w2t(const float* __restrict__ w2, float* __restrict__ w2t){
  int idx = blockIdx.x*256 + threadIdx.x;
  int g = idx >> 13, q = idx & 8191;
  int i = q & 63, o = q >> 6;
  w2t[idx] = w2[((size_t)i*128 + o)*192 + g];
}

// K6: Fy2 -> B-hat bf16 (g-unroll x2, float4 psiL reads).
__global__ void __launch_bounds__(256) k_fy2(const float* __restrict__ cst,
                                             const float* __restrict__ w2t,
                                             unsigned int* __restrict__ FyB){
  __shared__ __align__(16) float2 psiL[8*192];
  int cg  = blockIdx.x >> 5;
  int iog = blockIdx.x & 31;
  int tid = threadIdx.x;
  int q   = iog*256 + tid;
  int i   = q & 63, o = q >> 6;
  const float2* psi = (const float2*)(cst + OFF_PSI3) + (size_t)cg*8*192;
  for(int t=tid; t<1536; t+=256) psiL[t] = psi[t];
  __syncthreads();
  float2 acc[8];
  #pragma unroll
  for(int j=0;j<8;j++) acc[j] = make_float2(0.f,0.f);
  const float4* psiL4 = (const float4*)psiL;
  for(int g=0; g<192; g+=2){
    float w0 = w2t[(size_t)g*8192 + q];
    float w1 = w2t[(size_t)(g+1)*8192 + q];
    int gh = g >> 1;
    #pragma unroll
    for(int j=0;j<8;j++){
      float4 p = psiL4[j*96 + gh];
      acc[j].x += w0*p.x + w1*p.z;
      acc[j].y += w0*p.y + w1*p.w;
    }
  }
  #pragma unroll
  for(int j=0;j<8;j++){
    size_t base = (size_t)(cg*8+j)*16384;
    unsigned int r  = f2bf(acc[j].x);
    unsigned int im = f2bf(acc[j].y);
    unsigned int nim= f2bf(-acc[j].y);
    FyB[base + (size_t)(2*o  )*64 + i] = r  | (im << 16);
    FyB[base + (size_t)(2*o+1)*64 + i] = nim| (r  << 16);
  }
}

// K7: Fz2 via bf16 MFMA — Hermitian-halved: 344 blocks compute coef (l,mi,ni)
// with q = mi*c+ni <= (c*c-1)/2 and also emit the mirror coef (l, c-1-mi, c-1-ni)
// via Fz2[-m,-n] = (-1)^{m+n} conj(Fz2[m,n]). Halves Fy2 B-row traffic.
__global__ void __launch_bounds__(256) k_fz2(const unsigned int* __restrict__ FxB,
                                             const unsigned int* __restrict__ FyB,
                                             float* __restrict__ Fz2f){
  int p = blockIdx.x;
  int c, o3, q;
  if(p < 113)      { c=15; o3=455; q=p; }
  else if(p < 198) { c=13; o3=286; q=p-113; }
  else if(p < 259) { c=11; o3=165; q=p-198; }
  else if(p < 300) { c=9;  o3=84;  q=p-259; }
  else if(p < 325) { c=7;  o3=35;  q=p-300; }
  else if(p < 338) { c=5;  o3=10;  q=p-325; }
  else if(p < 343) { c=3;  o3=1;   q=p-338; }
  else             { c=1;  o3=0;   q=0; }
  int mi = q / c, ni = q - mi*c;
  int lh = c >> 1;

  int tid  = threadIdx.x;
  int lane = tid & 63, wv = tid >> 6;
  int m16  = lane & 15, quad = lane >> 4;

  int aoff = m16*128 + quad*8;
  int boff = (wv*64 + m16)*128 + quad*8;

  f32x4 acc0 = {0,0,0,0}, acc1 = {0,0,0,0}, acc2v = {0,0,0,0}, acc3 = {0,0,0,0};

  const unsigned short* FxS = (const unsigned short*)FxB;
  const unsigned short* FyS = (const unsigned short*)FyB;

  for(int kk=0; kk<c; kk++){
    const unsigned short* Arow = FxS + (size_t)(o3 + mi*c + kk)*2048;
    const unsigned short* Brow = FyS + (size_t)(o3 + ni*c + kk)*32768;
    #pragma unroll
    for(int ig=0; ig<4; ig++){
      bf16x8 af = *(const bf16x8*)(Arow + aoff + ig*32);
      bf16x8 b0 = *(const bf16x8*)(Brow + boff            + ig*32);
      bf16x8 b1 = *(const bf16x8*)(Brow + boff + 1*2048   + ig*32);
      bf16x8 b2 = *(const bf16x8*)(Brow + boff + 2*2048   + ig*32);
      bf16x8 b3 = *(const bf16x8*)(Brow + boff + 3*2048   + ig*32);
      acc0  = __builtin_amdgcn_mfma_f32_16x16x32_bf16(af, b0, acc0,  0,0,0);
      acc1  = __builtin_amdgcn_mfma_f32_16x16x32_bf16(af, b1, acc1,  0,0,0);
      acc2v = __builtin_amdgcn_mfma_f32_16x16x32_bf16(af, b2, acc2v, 0,0,0);
      acc3  = __builtin_amdgcn_mfma_f32_16x16x32_bf16(af, b3, acc3,  0,0,0);
    }
  }
  int coefC = o3 + mi*c + ni;
  float* dst = Fz2f + (size_t)coefC*4096;
  int npb = wv*64 + m16;
  #pragma unroll
  for(int r=0;r<4;r++){
    int b = quad*4 + r;
    dst[(size_t)b*256 + npb       ] = acc0[r];
    dst[(size_t)b*256 + npb + 16  ] = acc1[r];
    dst[(size_t)b*256 + npb + 32  ] = acc2v[r];
    dst[(size_t)b*256 + npb + 48  ] = acc3[r];
  }
  if(!(mi==lh && ni==lh)){
    int coefM = o3 + (c-1-mi)*c + (c-1-ni);
    float sg = (((mi+ni) + (m16&1)) & 1) ? -1.f : 1.f;
    float* dst2 = Fz2f + (size_t)coefM*4096;
    #pragma unroll
    for(int r=0;r<4;r++){
      int b = quad*4 + r;
      dst2[(size_t)b*256 + npb       ] = sg*acc0[r];
      dst2[(size_t)b*256 + npb + 16  ] = sg*acc1[r];
      dst2[(size_t)b*256 + npb + 32  ] = sg*acc2v[r];
      dst2[(size_t)b*256 + npb + 48  ] = sg*acc3[r];
    }
  }
}

// K8: slice2 — one WAVE per (b,o): 512 blocks x 4 waves, per-wave LDS regions,
// zero __syncthreads in the k2 loop (wave_fence = compiler fence + waitcnt drain).
__global__ void __launch_bounds__(256,4) k_slice2(const float* __restrict__ cst,
                                                  const float2* __restrict__ Fz2P,
                                                  float* __restrict__ featP){
  __shared__ float2 FzL[4][680];
  __shared__ float2 S2m[4][225];
  __shared__ float2 TAm[4][240];
  __shared__ float2 w16s[16];
  int tid = threadIdx.x;
  int wvi = tid >> 6, lane = tid & 63;
  int bo = blockIdx.x*4 + wvi;
  if(tid < 16){ float ang = (TWO_PI_F/16.0f)*tid; w16s[tid] = make_float2(cosf(ang), sinf(ang)); }
  float2* Fz = FzL[wvi];
  float2* S  = S2m[wvi];
  float2* T  = TAm[wvi];
  for(int t=lane; t<680; t+=64) Fz[t] = Fz2P[(size_t)t*2048 + bo];
  __syncthreads();   // covers w16s + Fz visibility (block-wide, once)
  const float* D2  = cst + OFF_D2;
  const float* WL2 = cst + OFF_WL2;
  float part = 0.f;
  for(int k2=0;k2<16;k2++){
    for(int e=lane; e<225; e+=64){
      int mi = e/15, ni = e - mi*15;
      int m = mi-7, n = ni-7;
      int am = m<0?-m:m, an = n<0?-n:n;
      int lmin = am>an?am:an;
      float2 acc = make_float2(0.f,0.f);
      for(int l=lmin;l<8;l++){
        int c = 2*l+1;
        int idx = off3d(l) + (m+l)*c + (n+l);
        float dv = D2[((size_t)idx<<4) + k2];
        float2 fzv = Fz[idx];
        acc.x += dv*fzv.x; acc.y += dv*fzv.y;
      }
      S[e] = acc;
    }
    wave_fence();
    for(int e=lane; e<240; e+=64){
      int mi = e >> 4, cc = e & 15;
      float2 acc = make_float2(0.f,0.f);
      for(int ni=0;ni<15;ni++){
        float2 sv = S[mi*15+ni];
        float2 w = w16s[((ni-7)*cc)&15];
        acc.x += sv.x*w.x - sv.y*w.y;
        acc.y += sv.x*w.y + sv.y*w.x;
      }
      T[e] = acc;
    }
    wave_fence();
    for(int e=lane; e<256; e+=64){
      int a = e >> 4, cc = e & 15;
      float acc = 0.f;
      for(int mi=0;mi<15;mi++){
        float2 tv = T[mi*16+cc];
        float2 w = w16s[((mi-7)*a)&15];
        acc += tv.x*w.x - tv.y*w.y;
      }
      if(acc > 0.f) part += WL2[k2]*acc;
    }
    wave_fence();
  }
  for(int s=32;s>0;s>>=1) part += __shfl_down(part, s, 64);
  if(lane==0) featP[bo] = part*(1.0f/256.0f);
}

// K9: out[b,j]
__global__ void k_out(const float* __restrict__ featP, const float* __restrict__ lin_w,
                      const float* __restrict__ lin_b, float* __restrict__ out){
  int t = threadIdx.x;
  if(t < 160){
    int b = t/10, j = t%10;
    float acc = lin_b[j];
    for(int o=0;o<128;o++) acc += featP[b*128+o]*lin_w[j*128+o];
    out[t] = acc;
  }
}

extern "C" void kernel_launch(void* const* d_in, const int* in_sizes, int n_in,
                              void* d_out, int out_size, void* d_ws, size_t ws_size,
                              hipStream_t stream){
  const float* x     = (const float*)d_in[0];
  const float* w1    = (const float*)d_in[1];
  const float* w2    = (const float*)d_in[2];
  const float* lin_w = (const float*)d_in[3];
  const float* lin_b = (const float*)d_in[4];
  float* out = (float*)d_out;
  if(ws_size < WS_NEEDED) return;
  char* ws = (char*)d_ws;
  float2* xf1  = (float2*)(ws + OFS_XF1);
  float2* FxP  = (float2*)(ws + OFS_FX);
  float2* FyP  = (float2*)(ws + OFS_FY1);
  unsigned int* FxB = (unsigned int*)(ws + OFS_FX2);
  unsigned int* FyB = (unsigned int*)(ws + OFS_FY2);
  float2* Fz2P = (float2*)(ws + OFS_FZ2);
  float*  w2tP = (float*)(ws + OFS_W2T);
  float*  featP= (float*)(ws + OFS_FEAT);
  const float* cst = g_const;

  k_fft_alpha<<<2048, 128, 0, stream>>>(x, xf1);
  k_fx      <<<64,   256, 0, stream>>>(cst, xf1, FxP);
  k_fy1     <<<64,   256, 0, stream>>>(cst, w1, FyP);
  k_conv1   <<<1024, 256, 0, stream>>>(cst, FxP, FyP, FxB);
  k_w2t     <<<6144, 256, 0, stream>>>(w2, w2tP);
  k_fy2     <<<2720, 256, 0, stream>>>(cst, w2tP, FyB);
  k_fz2     <<<344,  256, 0, stream>>>(FxB, FyB, (float*)Fz2P);
  k_slice2  <<<512,  256, 0, stream>>>(cst, Fz2P, featP);
  k_out     <<<1,    256, 0, stream>>>(featP, lin_w, lin_b, out);
}

// Round 16
// 598.079 us; speedup vs baseline: 1.1695x; 1.1695x over previous
//
#include <hip/hip_runtime.h>
#include <cmath>
#include <vector>
#include <algorithm>

// ---------------- constant table offsets (in floats) ----------------
enum : int {
  OFF_WIN  = 0,
  OFF_WL1  = 128,
  OFF_WL2  = 160,
  OFF_DCOL = 176,                  // 256*128
  OFF_D1A  = OFF_DCOL + 32768,     // 174592: (2l+1)*d, layout [(o3+idx)*32 + k]
  OFF_D1B  = OFF_D1A + 174592,     // 174592: 2pi*wl1[k]*d/1024, layout [(o3+idx)*32 + k]
  OFF_D2   = OFF_D1B + 174592,     // 10880: (2l+1)*d2, layout [(o3+idx)*16 + k2]
  OFF_PSI2 = OFF_D2 + 10880,       // 12288
  OFF_PSI3 = OFF_PSI2 + 12288,     // 261120
  CONST_TOTAL = OFF_PSI3 + 261120
};

// ---------------- workspace layout (bytes) ----------------
static constexpr size_t OFS_XF1  = 0;
static constexpr size_t OFS_FX   = 507904;
static constexpr size_t OFS_FY1  = 540672;
static constexpr size_t OFS_FX2  = 671744;     // bf16 A-hat
static constexpr size_t OFS_FY2  = 6242304;    // bf16 B-hat
static constexpr size_t OFS_FZ2  = 50806784;   // 680*2048 c64
static constexpr size_t OFS_W2T  = OFS_FZ2;    // w2t overlaps Fz2
static constexpr size_t OFS_FEAT = 61947904;
static constexpr size_t WS_NEEDED = 61956096;

static inline int off3h(int l){ return (4*l*l*l - l)/3; }

// ---------------- host-side constant construction ----------------
namespace {

double fact_[32];
void init_fact(){ fact_[0]=1.0; for(int i=1;i<32;i++) fact_[i]=fact_[i-1]*i; }

void wigner_d(int l, double beta, double* d){
  int n = 2*l+1;
  double cb = std::cos(beta*0.5), sb = std::sin(beta*0.5);
  for(int r=0;r<n;r++){ int mp = r-l;
    for(int c=0;c<n;c++){ int m = c-l;
      double f = std::sqrt(fact_[l+mp]*fact_[l-mp]*fact_[l+m]*fact_[l-m]);
      int s0 = std::max(0, m-mp), s1 = std::min(l+m, l-mp);
      double sum = 0;
      for(int s=s0;s<=s1;s++){
        double t = (((mp-m+s)&1)? -1.0 : 1.0)
                 / (fact_[l+m-s]*fact_[s]*fact_[mp-m+s]*fact_[l-mp-s]);
        t *= std::pow(cb, (double)(2*l+m-mp-2*s)) * std::pow(sb, (double)(mp-m+2*s));
        sum += t;
      }
      d[r*n+c] = f*sum;
    }
  }
}

void dh_weights(int b, double* w){
  for(int j=0;j<2*b;j++){
    double s = 0;
    for(int l=0;l<b;l++) s += std::sin((2.0*j+1)*(2.0*l+1)*M_PI/(4.0*b))/(2.0*l+1);
    w[j] = (2.0/b)*std::sin(M_PI*(2.0*j+1)/(4.0*b))*s;
  }
}

float* g_const = nullptr;

struct ConstInit {
  ConstInit(){
    init_fact();
    std::vector<float> h((size_t)CONST_TOTAL, 0.0f);
    std::vector<double> tmp(31*31);
    std::vector<double> wl1(32);
    { std::vector<double> w(128); dh_weights(64, w.data()); for(int i=0;i<128;i++) h[OFF_WIN+i]=(float)w[i]; }
    { dh_weights(16, wl1.data()); for(int i=0;i<32;i++)  h[OFF_WL1+i]=(float)wl1[i]; }
    { std::vector<double> w(16);  dh_weights(8,  w.data()); for(int i=0;i<16;i++)  h[OFF_WL2+i]=(float)w[i]; }
    for(int l=0;l<16;l++){ int n=2*l+1;
      for(int k=0;k<128;k++){
        wigner_d(l, M_PI*(2.0*k+1)/256.0, tmp.data());
        for(int mi=0;mi<n;mi++) h[OFF_DCOL + (size_t)(l*l+mi)*128 + k] = (float)tmp[mi*n + l];
      }
    }
    for(int l=0;l<16;l++){ int n=2*l+1;
      for(int k=0;k<32;k++){
        wigner_d(l, M_PI*(2.0*k+1)/64.0, tmp.data());
        for(int t=0;t<n*n;t++){
          size_t base = (size_t)(off3h(l)+t)*32 + k;
          h[OFF_D1A + base] = (float)((2*l+1)*tmp[t]);
          if(l < 8)
            h[OFF_D1B + base] = (float)(2.0*M_PI*wl1[k]*tmp[t]/1024.0);
        }
      }
    }
    for(int l=0;l<8;l++){ int n=2*l+1;
      for(int k=0;k<16;k++){
        wigner_d(l, M_PI*(2.0*k+1)/32.0, tmp.data());
        for(int t=0;t<n*n;t++)
          h[OFF_D2 + (size_t)(off3h(l)+t)*16 + k] = (float)((2*l+1)*tmp[t]);
      }
    }
    for(int l=0;l<16;l++){ int n=2*l+1;
      for(int i=0;i<3;i++){
        wigner_d(l, (i+1)*(M_PI/8.0)/3.0, tmp.data());
        for(int j=0;j<8;j++){
          double alpha = 2.0*M_PI*j/8.0;
          int g = i*8+j;
          for(int mi=0;mi<n;mi++){
            double d = tmp[mi*n + l];
            double th = (double)(mi-l)*alpha;
            size_t base = OFF_PSI2 + ((size_t)(l*l+mi)*24 + g)*2;
            h[base+0] = (float)( d*std::cos(th));
            h[base+1] = (float)(-d*std::sin(th));
          }
        }
      }
    }
    for(int l=0;l<8;l++){ int n=2*l+1;
      for(int i=0;i<3;i++){
        wigner_d(l, (i+1)*(M_PI/8.0)/3.0, tmp.data());
        for(int j=0;j<8;j++){
          double alpha = 2.0*M_PI*j/8.0;
          for(int kk=0;kk<8;kk++){
            double gamma = 2.0*M_PI*kk/8.0 - alpha;
            int g = (i*8+j)*8+kk;
            for(int mi=0;mi<n;mi++) for(int ni=0;ni<n;ni++){
              double d = tmp[mi*n+ni];
              double th = (double)(mi-l)*alpha + (double)(ni-l)*gamma;
              size_t base = OFF_PSI3 + (((size_t)off3h(l)+ (size_t)mi*n+ni)*192 + g)*2;
              h[base+0] = (float)( d*std::cos(th));
              h[base+1] = (float)(-d*std::sin(th));
            }
          }
        }
      }
    }
    hipMalloc((void**)&g_const, sizeof(float)*(size_t)CONST_TOTAL);
    hipMemcpy(g_const, h.data(), sizeof(float)*(size_t)CONST_TOTAL, hipMemcpyHostToDevice);
  }
};
ConstInit g_init_;

} // namespace

// ---------------- device helpers ----------------
__device__ __forceinline__ int off3d(int l){ return (4*l*l*l - l)/3; }
constexpr float TWO_PI_F = 6.28318530717958647692f;

__device__ __forceinline__ unsigned int f2bf(float f){
  union { float f; unsigned int u; } v; v.f = f;
  unsigned int r = v.u + 0x7FFFu + ((v.u >> 16) & 1u);
  return r >> 16;
}
__device__ __forceinline__ unsigned int pk2(float2 v){
  return f2bf(v.x) | (f2bf(v.y) << 16);
}
__device__ __forceinline__ float bflo(unsigned int u){
  union { unsigned int u; float f; } c; c.u = u << 16; return c.f;
}
__device__ __forceinline__ float bfhi(unsigned int u){
  union { unsigned int u; float f; } c; c.u = u & 0xffff0000u; return c.f;
}

typedef __attribute__((ext_vector_type(8))) short bf16x8;
typedef __attribute__((ext_vector_type(4))) float f32x4;

// K1: xf1[b,k,m] — 4-way a-split + LDS reduce
__global__ void k_fft_alpha(const float* __restrict__ x, float2* __restrict__ xf1){
  __shared__ float row[128];
  __shared__ float2 w128[128];
  __shared__ float2 red2[4][31];
  int r = blockIdx.x;
  int t = threadIdx.x;
  row[t] = x[(size_t)r*128 + t];
  float ang = (TWO_PI_F/128.0f)*t;
  w128[t] = make_float2(cosf(ang), sinf(ang));
  __syncthreads();
  int mi = t & 31, part = t >> 5;
  if(mi < 31){
    int m = mi - 15;
    float2 acc = make_float2(0.f,0.f);
    int a0 = part*32;
    for(int a=a0;a<a0+32;a++){
      float2 w = w128[(m*a)&127];
      acc.x += row[a]*w.x;
      acc.y -= row[a]*w.y;
    }
    red2[part][mi] = acc;
  }
  __syncthreads();
  if(t < 31){
    float2 s = red2[0][t];
    float2 s1 = red2[1][t], s2 = red2[2][t], s3 = red2[3][t];
    s.x += s1.x + s2.x + s3.x;
    s.y += s1.y + s2.y + s3.y;
    xf1[(size_t)r*31 + t] = s;
  }
}

// K2: Fx[c2][b] — 4-way k-split, LDS reduce
__global__ void k_fx(const float* __restrict__ cst, const float2* __restrict__ xf1,
                     float2* __restrict__ FxP){
  __shared__ float2 redL[256];
  int lp = threadIdx.x & 63;
  int kc = threadIdx.x >> 6;
  int idx = blockIdx.x*64 + lp;
  int c2 = idx >> 4, b = idx & 15;
  int l = 0; while((l+1)*(l+1) <= c2) l++;
  int m = (c2 - l*l) - l;
  const float* W  = cst + OFF_WIN;
  const float* DC = cst + OFF_DCOL + (size_t)c2*128;
  float2 acc = make_float2(0.f,0.f);
  int k0 = kc*32;
  for(int k=k0;k<k0+32;k++){
    float wv = W[k]*DC[k];
    float2 xv = xf1[((size_t)b*128+k)*31 + (m+15)];
    acc.x += wv*xv.x; acc.y += wv*xv.y;
  }
  redL[threadIdx.x] = acc;
  __syncthreads();
  if(kc == 0){
    float2 p1 = redL[lp+64], p2 = redL[lp+128], p3 = redL[lp+192];
    acc.x += p1.x + p2.x + p3.x;
    acc.y += p1.y + p2.y + p3.y;
    float s = TWO_PI_F/128.0f;
    FxP[(size_t)c2*16+b] = make_float2(acc.x*s, acc.y*s);
  }
}

// K3: Fy1[c2][o]
__global__ void k_fy1(const float* __restrict__ cst, const float* __restrict__ w1,
                      float2* __restrict__ FyP){
  int idx = blockIdx.x*blockDim.x + threadIdx.x;
  int c2 = idx >> 6, o = idx & 63;
  const float2* psi = (const float2*)(cst + OFF_PSI2) + (size_t)c2*24;
  const float* w1r = w1 + (size_t)o*24;
  float2 acc = make_float2(0.f,0.f);
  for(int g=0;g<24;g++){
    float wv = w1r[g];
    float2 p = psi[g];
    acc.x += wv*p.x; acc.y += wv*p.y;
  }
  FyP[(size_t)c2*64+o] = acc;
}

// K4: fused first conv — exact R14 version (measured best: ~300 us).
__global__ void __launch_bounds__(256,4) k_conv1(const float* __restrict__ cst,
                                                 const float2* __restrict__ FxP,
                                                 const float2* __restrict__ FyP,
                                                 unsigned int* __restrict__ FxB){
  __shared__ __align__(16) char L[39936];
  float2* FxL = (float2*)L;
  float2* FyL = FxL + 256;
  float2* SB  = (float2*)(L + 4096);
  unsigned int* yBu = (unsigned int*)(L + 4096);
  float2* XfB = (float2*)(L + 4096);
  unsigned int* TBu = (unsigned int*)(L + 23936);
  float2* T2B = (float2*)(L + 23936);
  float2* acc2= (float2*)(L + 34176);
  float2* w32 = (float2*)(L + 39616);
  int*    o3T = (int*)(L + 39872);

  int b = blockIdx.x >> 6, o = blockIdx.x & 63;
  int tid = threadIdx.x;
  if(tid < 32){ float ang = (TWO_PI_F/32.0f)*tid; w32[tid] = make_float2(cosf(ang), sinf(ang)); }
  if(tid < 16){ int l = tid; o3T[l] = (4*l*l*l - l)/3; }
  FxL[tid] = FxP[(size_t)tid*16 + b];
  FyL[tid] = FyP[(size_t)tid*64 + o];
  for(int t=tid; t<680; t+=256) acc2[t] = make_float2(0.f,0.f);

  const float* D1A = cst + OFF_D1A;
  const float* D1B = cst + OFF_D1B;

  for(int kt=0; kt<8; kt++){
    int k0 = kt*4;
    __syncthreads();
    for(int t=tid; t<496; t+=256){
      int mi = t/31, niq = t - mi*31;
      int n = niq-15;
      int an = n<0?-n:n;
      int lmin = mi>an?mi:an;
      float2 s0={0,0},s1={0,0},s2={0,0},s3={0,0};
      for(int l=lmin;l<16;l++){
        int c = 2*l+1, l2 = l*l;
        float2 fx = FxL[l2+l+mi];
        float2 fy = FyL[l2+(n+l)];
        float zx = fx.x*fy.x + fx.y*fy.y;
        float zy = fx.y*fy.x - fx.x*fy.y;
        const float4* dp = (const float4*)(D1A + (((size_t)o3T[l] + (mi+l)*c + (n+l))<<5) + k0);
        float4 d0 = dp[0];
        s0.x += d0.x*zx; s0.y += d0.x*zy;
        s1.x += d0.y*zx; s1.y += d0.y*zy;
        s2.x += d0.z*zx; s2.y += d0.z*zy;
        s3.x += d0.w*zx; s3.y += d0.w*zy;
      }
      float2* sp = SB + (size_t)t*5;
      sp[0]=s0; sp[1]=s1; sp[2]=s2; sp[3]=s3;
    }
    __syncthreads();
    {
      int mi = tid >> 4, cp = tid & 15;
      float2 a0[4], a1[4];
      #pragma unroll
      for(int j=0;j<4;j++){ a0[j]=make_float2(0,0); a1[j]=make_float2(0,0); }
      float2 step = w32[cp];
      float2 wv = w32[(15*cp)&31];
      float2 cur = make_float2(wv.x, -wv.y);
      const float2* srow = SB + (size_t)(mi*31)*5;
      for(int nb=0; nb<31; nb++){
        float2 q0 = srow[nb*5+0], q1 = srow[nb*5+1], q2 = srow[nb*5+2], q3 = srow[nb*5+3];
        float px, py;
        bool odd = (nb & 1);
        #define K1STEP(QX,QY,J) \
          px = QX*cur.x - QY*cur.y; py = QX*cur.y + QY*cur.x; \
          a0[J].x += px; a0[J].y += py; \
          if(odd){ a1[J].x += px; a1[J].y += py; } else { a1[J].x -= px; a1[J].y -= py; }
        K1STEP(q0.x,q0.y,0) K1STEP(q1.x,q1.y,1)
        K1STEP(q2.x,q2.y,2) K1STEP(q3.x,q3.y,3)
        #undef K1STEP
        float nx = cur.x*step.x - cur.y*step.y;
        cur.y = cur.x*step.y + cur.y*step.x;
        cur.x = nx;
      }
      unsigned int* tp0 = TBu + (size_t)(mi*32+cp)*5;
      tp0[0]=pk2(a0[0]); tp0[1]=pk2(a0[1]); tp0[2]=pk2(a0[2]); tp0[3]=pk2(a0[3]);
      unsigned int* tp1 = TBu + (size_t)(mi*32+cp+16)*5;
      tp1[0]=pk2(a1[0]); tp1[1]=pk2(a1[1]); tp1[2]=pk2(a1[2]); tp1[3]=pk2(a1[3]);
    }
    __syncthreads();
    {
      int c = tid & 31, aq = tid >> 5;
      float y0[4],y1[4],y2[4],y3[4], t0x[4];
      {
        const unsigned int* t0p = TBu + (size_t)c*5;
        t0x[0]=bflo(t0p[0]); t0x[1]=bflo(t0p[1]); t0x[2]=bflo(t0p[2]); t0x[3]=bflo(t0p[3]);
      }
      #pragma unroll
      for(int j=0;j<4;j++){ y0[j]=0; y1[j]=0; y2[j]=0; y3[j]=0; }
      #pragma unroll
      for(int m=1;m<16;m++){
        float2 w = w32[(m*aq)&31];
        const unsigned int* tp = TBu + (size_t)(m*32+c)*5;
        unsigned int d0=tp[0], d1=tp[1], d2=tp[2], d3=tp[3];
        float tx[4] = {bflo(d0),bflo(d1),bflo(d2),bflo(d3)};
        float ty[4] = {bfhi(d0),bfhi(d1),bfhi(d2),bfhi(d3)};
        #pragma unroll
        for(int j=0;j<4;j++){
          float px = tx[j]*w.x - ty[j]*w.y;
          float py = tx[j]*w.y + ty[j]*w.x;
          y0[j] += px;
          int r = m & 3;
          if(r==0){ y1[j] += px; y3[j] += px; }
          else if(r==1){ y1[j] -= py; y3[j] += py; }
          else if(r==2){ y1[j] -= px; y3[j] -= px; }
          else { y1[j] += py; y3[j] -= py; }
          y2[j] += (m&1)? -px : px;
        }
      }
      #define YWRITE(A, YV) { \
        float v0 = t0x[0]+2.f*YV[0], v1 = t0x[1]+2.f*YV[1], v2 = t0x[2]+2.f*YV[2], v3 = t0x[3]+2.f*YV[3]; \
        v0 = v0>0?v0:0; v1 = v1>0?v1:0; v2 = v2>0?v2:0; v3 = v3>0?v3:0; \
        unsigned int* yp = yBu + ((size_t)(A)*32 + c)*3; \
        yp[0] = f2bf(v0) | (f2bf(v1)<<16); \
        yp[1] = f2bf(v2) | (f2bf(v3)<<16); }
      YWRITE(aq,    y0)
      YWRITE(aq+8,  y1)
      YWRITE(aq+16, y2)
      YWRITE(aq+24, y3)
      #undef YWRITE
    }
    __syncthreads();
    {
      int mp = tid >> 5, c4 = tid & 31;
      float2 t2[4];
      #pragma unroll
      for(int j=0;j<4;j++) t2[j]=make_float2(0,0);
      for(int a=0;a<32;a++){
        float2 w = w32[(mp*a)&31];
        const unsigned int* yp = yBu + ((size_t)a*32 + c4)*3;
        unsigned int d0 = yp[0], d1 = yp[1];
        float yv[4] = {bflo(d0), bfhi(d0), bflo(d1), bfhi(d1)};
        #pragma unroll
        for(int j=0;j<4;j++){
          t2[j].x += yv[j]*w.x;
          t2[j].y -= yv[j]*w.y;
        }
      }
      float2* tp = T2B + (size_t)(mp*32+c4)*5;
      tp[0]=t2[0]; tp[1]=t2[1]; tp[2]=t2[2]; tp[3]=t2[3];
    }
    __syncthreads();
    if(tid < 120){
      int mp = tid/15, npq = tid - mp*15;
      int np = npq-7;
      float2 xf[4];
      #pragma unroll
      for(int j=0;j<4;j++) xf[j]=make_float2(0,0);
      float2 wv = w32[np&31];
      float2 step = make_float2(wv.x, -wv.y);
      float2 cur = make_float2(1.f, 0.f);
      const float2* trow = T2B + (size_t)(mp*32)*5;
      for(int c=0;c<32;c++){
        float2 q0 = trow[c*5+0], q1 = trow[c*5+1], q2 = trow[c*5+2], q3 = trow[c*5+3];
        float tx[4] = {q0.x,q1.x,q2.x,q3.x};
        float ty[4] = {q0.y,q1.y,q2.y,q3.y};
        #pragma unroll
        for(int j=0;j<4;j++){
          xf[j].x += tx[j]*cur.x - ty[j]*cur.y;
          xf[j].y += tx[j]*cur.y + ty[j]*cur.x;
        }
        float nx = cur.x*step.x - cur.y*step.y;
        cur.y = cur.x*step.y + cur.y*step.x;
        cur.x = nx;
      }
      float2* xp = XfB + (size_t)tid*5;
      xp[0]=xf[0]; xp[1]=xf[1]; xp[2]=xf[2]; xp[3]=xf[3];
    }
    __syncthreads();
    if(tid < 225){
      int mi2 = tid/15, ni2 = tid - mi2*15;
      int mp = mi2-7, np = ni2-7;
      float2 xf[4];
      if(mp >= 0){
        const float2* xp = XfB + (size_t)(mp*15+ni2)*5;
        xf[0]=xp[0]; xf[1]=xp[1]; xf[2]=xp[2]; xf[3]=xp[3];
      } else {
        const float2* xp = XfB + (size_t)((-mp)*15+(14-ni2))*5;
        float2 q0=xp[0],q1=xp[1],q2=xp[2],q3=xp[3];
        xf[0]=make_float2(q0.x,-q0.y); xf[1]=make_float2(q1.x,-q1.y);
        xf[2]=make_float2(q2.x,-q2.y); xf[3]=make_float2(q3.x,-q3.y);
      }
      int am = mp<0?-mp:mp, an = np<0?-np:np;
      int lmin = am>an?am:an;
      for(int l=lmin;l<8;l++){
        int c2 = 2*l+1;
        int cidx = o3T[l] + (mp+l)*c2 + (np+l);
        const float4* dp = (const float4*)(D1B + (((size_t)cidx)<<5) + k0);
        float4 d0 = dp[0];
        float rx = d0.x*xf[0].x + d0.y*xf[1].x + d0.z*xf[2].x + d0.w*xf[3].x;
        float ry = d0.x*xf[0].y + d0.y*xf[1].y + d0.z*xf[2].y + d0.w*xf[3].y;
        float2 cur = acc2[cidx];
        cur.x += rx; cur.y += ry;
        acc2[cidx] = cur;
      }
    }
  }
  __syncthreads();
  for(int t=tid; t<680; t+=256){
    float2 v = acc2[t];
    unsigned int pk = f2bf(v.x) | (f2bf(v.y) << 16);
    FxB[(size_t)t*1024 + b*64 + o] = pk;
  }
}

// K5: transpose w2 [i*128+o][192g] -> w2t [g][o*64+i]
__global__ void k_w2t(const float* __restrict__ w2, float* __restrict__ w2t){
  int idx = blockIdx.x*256 + threadIdx.x;
  int g = idx >> 13, q = idx & 8191;
  int i = q & 63, o = q >> 6;
  w2t[idx] = w2[((size_t)i*128 + o)*192 + g];
}

// K6: Fy2 -> B-hat bf16 (g-unroll x2, float4 psiL reads).
__global__ void __launch_bounds__(256) k_fy2(const float* __restrict__ cst,
                                             const float* __restrict__ w2t,
                                             unsigned int* __restrict__ FyB){
  __shared__ __align__(16) float2 psiL[8*192];
  int cg  = blockIdx.x >> 5;
  int iog = blockIdx.x & 31;
  int tid = threadIdx.x;
  int q   = iog*256 + tid;
  int i   = q & 63, o = q >> 6;
  const float2* psi = (const float2*)(cst + OFF_PSI3) + (size_t)cg*8*192;
  for(int t=tid; t<1536; t+=256) psiL[t] = psi[t];
  __syncthreads();
  float2 acc[8];
  #pragma unroll
  for(int j=0;j<8;j++) acc[j] = make_float2(0.f,0.f);
  const float4* psiL4 = (const float4*)psiL;
  for(int g=0; g<192; g+=2){
    float w0 = w2t[(size_t)g*8192 + q];
    float w1 = w2t[(size_t)(g+1)*8192 + q];
    int gh = g >> 1;
    #pragma unroll
    for(int j=0;j<8;j++){
      float4 p = psiL4[j*96 + gh];
      acc[j].x += w0*p.x + w1*p.z;
      acc[j].y += w0*p.y + w1*p.w;
    }
  }
  #pragma unroll
  for(int j=0;j<8;j++){
    size_t base = (size_t)(cg*8+j)*16384;
    unsigned int r  = f2bf(acc[j].x);
    unsigned int im = f2bf(acc[j].y);
    unsigned int nim= f2bf(-acc[j].y);
    FyB[base + (size_t)(2*o  )*64 + i] = r  | (im << 16);
    FyB[base + (size_t)(2*o+1)*64 + i] = nim| (r  << 16);
  }
}

// K7: Fz2 via bf16 MFMA — Hermitian-halved WITH parallelism fix:
// grid = 344 coef-halves x 2 N-splits = 688 blocks (~2.7/CU).
// Block (p,nb): computes coef (l,mi,ni), n' in [nb*128, nb*128+128).
// Each wave covers 32 n'-rows (2 tiles), 2 accumulators. Mirror coef
// (l,c-1-mi,c-1-ni) written via Fz2[-m,-n] = (-1)^{m+n} conj(.).
__global__ void __launch_bounds__(256) k_fz2(const unsigned int* __restrict__ FxB,
                                             const unsigned int* __restrict__ FyB,
                                             float* __restrict__ Fz2f){
  int p = blockIdx.x >> 1, nb = blockIdx.x & 1;
  int c, o3, q;
  if(p < 113)      { c=15; o3=455; q=p; }
  else if(p < 198) { c=13; o3=286; q=p-113; }
  else if(p < 259) { c=11; o3=165; q=p-198; }
  else if(p < 300) { c=9;  o3=84;  q=p-259; }
  else if(p < 325) { c=7;  o3=35;  q=p-300; }
  else if(p < 338) { c=5;  o3=10;  q=p-325; }
  else if(p < 343) { c=3;  o3=1;   q=p-338; }
  else             { c=1;  o3=0;   q=0; }
  int mi = q / c, ni = q - mi*c;
  int lh = c >> 1;

  int tid  = threadIdx.x;
  int lane = tid & 63, wv = tid >> 6;
  int m16  = lane & 15, quad = lane >> 4;

  int nrow = nb*128 + wv*32 + m16;           // base n'-row for this wave-lane
  int aoff = m16*128 + quad*8;
  int boff = nrow*128 + quad*8;

  f32x4 acc0 = {0,0,0,0}, acc1 = {0,0,0,0};

  const unsigned short* FxS = (const unsigned short*)FxB;
  const unsigned short* FyS = (const unsigned short*)FyB;

  for(int kk=0; kk<c; kk++){
    const unsigned short* Arow = FxS + (size_t)(o3 + mi*c + kk)*2048;
    const unsigned short* Brow = FyS + (size_t)(o3 + ni*c + kk)*32768;
    #pragma unroll
    for(int ig=0; ig<4; ig++){
      bf16x8 af = *(const bf16x8*)(Arow + aoff + ig*32);
      bf16x8 b0 = *(const bf16x8*)(Brow + boff          + ig*32);
      bf16x8 b1 = *(const bf16x8*)(Brow + boff + 2048   + ig*32);   // +16 n'-rows
      acc0 = __builtin_amdgcn_mfma_f32_16x16x32_bf16(af, b0, acc0, 0,0,0);
      acc1 = __builtin_amdgcn_mfma_f32_16x16x32_bf16(af, b1, acc1, 0,0,0);
    }
  }
  int coefC = o3 + mi*c + ni;
  float* dst = Fz2f + (size_t)coefC*4096;
  int npb = nrow;
  #pragma unroll
  for(int r=0;r<4;r++){
    int b = quad*4 + r;
    dst[(size_t)b*256 + npb     ] = acc0[r];
    dst[(size_t)b*256 + npb + 16] = acc1[r];
  }
  if(!(mi==lh && ni==lh)){
    int coefM = o3 + (c-1-mi)*c + (c-1-ni);
    float sg = (((mi+ni) + (npb&1)) & 1) ? -1.f : 1.f;
    float* dst2 = Fz2f + (size_t)coefM*4096;
    #pragma unroll
    for(int r=0;r<4;r++){
      int b = quad*4 + r;
      dst2[(size_t)b*256 + npb     ] = sg*acc0[r];
      dst2[(size_t)b*256 + npb + 16] = sg*acc1[r];
    }
  }
}

// K8: slice2 — R14 block version (measured good), k-contiguous D2.
__global__ void __launch_bounds__(256) k_slice2(const float* __restrict__ cst,
                                                const float2* __restrict__ Fz2P,
                                                float* __restrict__ featP){
  __shared__ float2 FzL[680];
  __shared__ float2 S2[225];
  __shared__ float2 TA[240];
  __shared__ float2 w16[16];
  __shared__ float red[256];
  int bo = blockIdx.x;
  int tid = threadIdx.x;
  if(tid < 16){ float ang = (TWO_PI_F/16.0f)*tid; w16[tid] = make_float2(cosf(ang), sinf(ang)); }
  for(int t=tid; t<680; t+=256) FzL[t] = Fz2P[(size_t)t*2048 + bo];
  __syncthreads();
  const float* D2  = cst + OFF_D2;
  const float* WL2 = cst + OFF_WL2;
  float part = 0.f;
  for(int k2=0;k2<16;k2++){
    if(tid < 225){
      int mi = tid/15, ni = tid%15;
      int m = mi-7, n = ni-7;
      int am = m<0?-m:m, an = n<0?-n:n;
      int lmin = am>an?am:an;
      float2 acc = make_float2(0.f,0.f);
      for(int l=lmin;l<8;l++){
        int c = 2*l+1;
        int idx = off3d(l) + (m+l)*c + (n+l);
        float dv = D2[((size_t)idx<<4) + k2];
        float2 fzv = FzL[idx];
        acc.x += dv*fzv.x; acc.y += dv*fzv.y;
      }
      S2[tid] = acc;
    }
    __syncthreads();
    if(tid < 240){
      int mi = tid >> 4, c = tid & 15;
      float2 acc = make_float2(0.f,0.f);
      for(int ni=0;ni<15;ni++){
        float2 sv = S2[mi*15+ni];
        float2 w = w16[((ni-7)*c)&15];
        acc.x += sv.x*w.x - sv.y*w.y;
        acc.y += sv.x*w.y + sv.y*w.x;
      }
      TA[mi*16+c] = acc;
    }
    __syncthreads();
    {
      int a = tid >> 4, c = tid & 15;
      float acc = 0.f;
      for(int mi=0;mi<15;mi++){
        float2 tv = TA[mi*16+c];
        float2 w = w16[((mi-7)*a)&15];
        acc += tv.x*w.x - tv.y*w.y;
      }
      if(acc > 0.f) part += WL2[k2]*acc;
    }
    __syncthreads();
  }
  red[tid] = part;
  __syncthreads();
  for(int s=128;s>0;s>>=1){ if(tid<s) red[tid]+=red[tid+s]; __syncthreads(); }
  if(tid==0) featP[bo] = red[0]*(1.0f/256.0f);
}

// K9: out[b,j]
__global__ void k_out(const float* __restrict__ featP, const float* __restrict__ lin_w,
                      const float* __restrict__ lin_b, float* __restrict__ out){
  int t = threadIdx.x;
  if(t < 160){
    int b = t/10, j = t%10;
    float acc = lin_b[j];
    for(int o=0;o<128;o++) acc += featP[b*128+o]*lin_w[j*128+o];
    out[t] = acc;
  }
}

extern "C" void kernel_launch(void* const* d_in, const int* in_sizes, int n_in,
                              void* d_out, int out_size, void* d_ws, size_t ws_size,
                              hipStream_t stream){
  const float* x     = (const float*)d_in[0];
  const float* w1    = (const float*)d_in[1];
  const float* w2    = (const float*)d_in[2];
  const float* lin_w = (const float*)d_in[3];
  const float* lin_b = (const float*)d_in[4];
  float* out = (float*)d_out;
  if(ws_size < WS_NEEDED) return;
  char* ws = (char*)d_ws;
  float2* xf1  = (float2*)(ws + OFS_XF1);
  float2* FxP  = (float2*)(ws + OFS_FX);
  float2* FyP  = (float2*)(ws + OFS_FY1);
  unsigned int* FxB = (unsigned int*)(ws + OFS_FX2);
  unsigned int* FyB = (unsigned int*)(ws + OFS_FY2);
  float2* Fz2P = (float2*)(ws + OFS_FZ2);
  float*  w2tP = (float*)(ws + OFS_W2T);
  float*  featP= (float*)(ws + OFS_FEAT);
  const float* cst = g_const;

  k_fft_alpha<<<2048, 128, 0, stream>>>(x, xf1);
  k_fx      <<<64,   256, 0, stream>>>(cst, xf1, FxP);
  k_fy1     <<<64,   256, 0, stream>>>(cst, w1, FyP);
  k_conv1   <<<1024, 256, 0, stream>>>(cst, FxP, FyP, FxB);
  k_w2t     <<<6144, 256, 0, stream>>>(w2, w2tP);
  k_fy2     <<<2720, 256, 0, stream>>>(cst, w2tP, FyB);
  k_fz2     <<<688,  256, 0, stream>>>(FxB, FyB, (float*)Fz2P);
  k_slice2  <<<2048, 256, 0, stream>>>(cst, Fz2P, featP);
  k_out     <<<1,    256, 0, stream>>>(featP, lin_w, lin_b, out);
}

// Round 17
// 529.942 us; speedup vs baseline: 1.3198x; 1.1286x over previous
//
#include <hip/hip_runtime.h>
#include <cmath>
#include <vector>
#include <algorithm>

// ---------------- constant table offsets (in floats) ----------------
enum : int {
  OFF_WIN  = 0,
  OFF_WL1  = 128,
  OFF_WL2  = 160,
  OFF_DCOL = 176,                  // 256*128
  OFF_D1A  = OFF_DCOL + 32768,     // 174592: (2l+1)*d, layout [(o3+idx)*32 + k]
  OFF_D1B  = OFF_D1A + 174592,     // 174592: 2pi*wl1[k]*d/1024, layout [(o3+idx)*32 + k]
  OFF_D2   = OFF_D1B + 174592,     // 10880: (2l+1)*d2, layout [(o3+idx)*16 + k2]
  OFF_PSI2 = OFF_D2 + 10880,       // 12288
  OFF_PSI3 = OFF_PSI2 + 12288,     // 261120
  OFF_PSIB = OFF_PSI3 + 261120,    // 132096 floats = 43mt x 2reim x 6ks x 64lane x 8 bf16
  CONST_TOTAL = OFF_PSIB + 132096
};

// ---------------- workspace layout (bytes) ----------------
static constexpr size_t OFS_XF1  = 0;
static constexpr size_t OFS_FX   = 507904;
static constexpr size_t OFS_FY1  = 540672;
static constexpr size_t OFS_FX2  = 671744;     // bf16 A-hat
static constexpr size_t OFS_FY2  = 6242304;    // bf16 B-hat
static constexpr size_t OFS_FZ2  = 50806784;   // 680*2048 c64
static constexpr size_t OFS_W2B  = OFS_FZ2;    // bf16 w2 repack (3 MB), dead before Fz2 written
static constexpr size_t OFS_FEAT = 61947904;
static constexpr size_t WS_NEEDED = 61956096;

static inline int off3h(int l){ return (4*l*l*l - l)/3; }

// ---------------- host-side constant construction ----------------
namespace {

double fact_[32];
void init_fact(){ fact_[0]=1.0; for(int i=1;i<32;i++) fact_[i]=fact_[i-1]*i; }

void wigner_d(int l, double beta, double* d){
  int n = 2*l+1;
  double cb = std::cos(beta*0.5), sb = std::sin(beta*0.5);
  for(int r=0;r<n;r++){ int mp = r-l;
    for(int c=0;c<n;c++){ int m = c-l;
      double f = std::sqrt(fact_[l+mp]*fact_[l-mp]*fact_[l+m]*fact_[l-m]);
      int s0 = std::max(0, m-mp), s1 = std::min(l+m, l-mp);
      double sum = 0;
      for(int s=s0;s<=s1;s++){
        double t = (((mp-m+s)&1)? -1.0 : 1.0)
                 / (fact_[l+m-s]*fact_[s]*fact_[mp-m+s]*fact_[l-mp-s]);
        t *= std::pow(cb, (double)(2*l+m-mp-2*s)) * std::pow(sb, (double)(mp-m+2*s));
        sum += t;
      }
      d[r*n+c] = f*sum;
    }
  }
}

void dh_weights(int b, double* w){
  for(int j=0;j<2*b;j++){
    double s = 0;
    for(int l=0;l<b;l++) s += std::sin((2.0*j+1)*(2.0*l+1)*M_PI/(4.0*b))/(2.0*l+1);
    w[j] = (2.0/b)*std::sin(M_PI*(2.0*j+1)/(4.0*b))*s;
  }
}

float* g_const = nullptr;

struct ConstInit {
  ConstInit(){
    init_fact();
    std::vector<float> h((size_t)CONST_TOTAL, 0.0f);
    std::vector<double> tmp(31*31);
    std::vector<double> wl1(32);
    { std::vector<double> w(128); dh_weights(64, w.data()); for(int i=0;i<128;i++) h[OFF_WIN+i]=(float)w[i]; }
    { dh_weights(16, wl1.data()); for(int i=0;i<32;i++)  h[OFF_WL1+i]=(float)wl1[i]; }
    { std::vector<double> w(16);  dh_weights(8,  w.data()); for(int i=0;i<16;i++)  h[OFF_WL2+i]=(float)w[i]; }
    for(int l=0;l<16;l++){ int n=2*l+1;
      for(int k=0;k<128;k++){
        wigner_d(l, M_PI*(2.0*k+1)/256.0, tmp.data());
        for(int mi=0;mi<n;mi++) h[OFF_DCOL + (size_t)(l*l+mi)*128 + k] = (float)tmp[mi*n + l];
      }
    }
    for(int l=0;l<16;l++){ int n=2*l+1;
      for(int k=0;k<32;k++){
        wigner_d(l, M_PI*(2.0*k+1)/64.0, tmp.data());
        for(int t=0;t<n*n;t++){
          size_t base = (size_t)(off3h(l)+t)*32 + k;
          h[OFF_D1A + base] = (float)((2*l+1)*tmp[t]);
          if(l < 8)
            h[OFF_D1B + base] = (float)(2.0*M_PI*wl1[k]*tmp[t]/1024.0);
        }
      }
    }
    for(int l=0;l<8;l++){ int n=2*l+1;
      for(int k=0;k<16;k++){
        wigner_d(l, M_PI*(2.0*k+1)/32.0, tmp.data());
        for(int t=0;t<n*n;t++)
          h[OFF_D2 + (size_t)(off3h(l)+t)*16 + k] = (float)((2*l+1)*tmp[t]);
      }
    }
    for(int l=0;l<16;l++){ int n=2*l+1;
      for(int i=0;i<3;i++){
        wigner_d(l, (i+1)*(M_PI/8.0)/3.0, tmp.data());
        for(int j=0;j<8;j++){
          double alpha = 2.0*M_PI*j/8.0;
          int g = i*8+j;
          for(int mi=0;mi<n;mi++){
            double d = tmp[mi*n + l];
            double th = (double)(mi-l)*alpha;
            size_t base = OFF_PSI2 + ((size_t)(l*l+mi)*24 + g)*2;
            h[base+0] = (float)( d*std::cos(th));
            h[base+1] = (float)(-d*std::sin(th));
          }
        }
      }
    }
    for(int l=0;l<8;l++){ int n=2*l+1;
      for(int i=0;i<3;i++){
        wigner_d(l, (i+1)*(M_PI/8.0)/3.0, tmp.data());
        for(int j=0;j<8;j++){
          double alpha = 2.0*M_PI*j/8.0;
          for(int kk=0;kk<8;kk++){
            double gamma = 2.0*M_PI*kk/8.0 - alpha;
            int g = (i*8+j)*8+kk;
            for(int mi=0;mi<n;mi++) for(int ni=0;ni<n;ni++){
              double d = tmp[mi*n+ni];
              double th = (double)(mi-l)*alpha + (double)(ni-l)*gamma;
              size_t base = OFF_PSI3 + (((size_t)off3h(l)+ (size_t)mi*n+ni)*192 + g)*2;
              h[base+0] = (float)( d*std::cos(th));
              h[base+1] = (float)(-d*std::sin(th));
            }
          }
        }
      }
    }
    // PSIB: MFMA A-fragment bf16 table for fy2 GEMM.
    // [mt 43][reim 2][ks 6][lane 64][j 8]: coef = mt*16+(lane&15), g = ks*32+(lane>>4)*8+j
    {
      auto hf2bf = [](float f)->unsigned short{
        union{float f; unsigned int u;} v; v.f=f;
        unsigned int r = v.u + 0x7FFFu + ((v.u>>16)&1u);
        return (unsigned short)(r>>16);
      };
      unsigned short* pb = (unsigned short*)(h.data() + OFF_PSIB);
      for(int mt=0; mt<43; mt++)
       for(int reim=0; reim<2; reim++)
        for(int ks=0; ks<6; ks++)
         for(int lane=0; lane<64; lane++)
          for(int j=0; j<8; j++){
            int coef = mt*16 + (lane&15);
            int g = ks*32 + (lane>>4)*8 + j;
            float v = 0.f;
            if(coef < 680) v = h[OFF_PSI3 + ((size_t)coef*192+g)*2 + reim];
            pb[((((size_t)mt*2+reim)*6+ks)*64+lane)*8+j] = hf2bf(v);
          }
    }
    hipMalloc((void**)&g_const, sizeof(float)*(size_t)CONST_TOTAL);
    hipMemcpy(g_const, h.data(), sizeof(float)*(size_t)CONST_TOTAL, hipMemcpyHostToDevice);
  }
};
ConstInit g_init_;

} // namespace

// ---------------- device helpers ----------------
__device__ __forceinline__ int off3d(int l){ return (4*l*l*l - l)/3; }
constexpr float TWO_PI_F = 6.28318530717958647692f;

__device__ __forceinline__ unsigned int f2bf(float f){
  union { float f; unsigned int u; } v; v.f = f;
  unsigned int r = v.u + 0x7FFFu + ((v.u >> 16) & 1u);
  return r >> 16;
}
__device__ __forceinline__ unsigned int pk2(float2 v){
  return f2bf(v.x) | (f2bf(v.y) << 16);
}
__device__ __forceinline__ float bflo(unsigned int u){
  union { unsigned int u; float f; } c; c.u = u << 16; return c.f;
}
__device__ __forceinline__ float bfhi(unsigned int u){
  union { unsigned int u; float f; } c; c.u = u & 0xffff0000u; return c.f;
}

typedef __attribute__((ext_vector_type(8))) short bf16x8;
typedef __attribute__((ext_vector_type(4))) float f32x4;

// K1: xf1[b,k,m] — 4-way a-split + LDS reduce
__global__ void k_fft_alpha(const float* __restrict__ x, float2* __restrict__ xf1){
  __shared__ float row[128];
  __shared__ float2 w128[128];
  __shared__ float2 red2[4][31];
  int r = blockIdx.x;
  int t = threadIdx.x;
  row[t] = x[(size_t)r*128 + t];
  float ang = (TWO_PI_F/128.0f)*t;
  w128[t] = make_float2(cosf(ang), sinf(ang));
  __syncthreads();
  int mi = t & 31, part = t >> 5;
  if(mi < 31){
    int m = mi - 15;
    float2 acc = make_float2(0.f,0.f);
    int a0 = part*32;
    for(int a=a0;a<a0+32;a++){
      float2 w = w128[(m*a)&127];
      acc.x += row[a]*w.x;
      acc.y -= row[a]*w.y;
    }
    red2[part][mi] = acc;
  }
  __syncthreads();
  if(t < 31){
    float2 s = red2[0][t];
    float2 s1 = red2[1][t], s2 = red2[2][t], s3 = red2[3][t];
    s.x += s1.x + s2.x + s3.x;
    s.y += s1.y + s2.y + s3.y;
    xf1[(size_t)r*31 + t] = s;
  }
}

// K2: Fx[c2][b] — 4-way k-split, LDS reduce
__global__ void k_fx(const float* __restrict__ cst, const float2* __restrict__ xf1,
                     float2* __restrict__ FxP){
  __shared__ float2 redL[256];
  int lp = threadIdx.x & 63;
  int kc = threadIdx.x >> 6;
  int idx = blockIdx.x*64 + lp;
  int c2 = idx >> 4, b = idx & 15;
  int l = 0; while((l+1)*(l+1) <= c2) l++;
  int m = (c2 - l*l) - l;
  const float* W  = cst + OFF_WIN;
  const float* DC = cst + OFF_DCOL + (size_t)c2*128;
  float2 acc = make_float2(0.f,0.f);
  int k0 = kc*32;
  for(int k=k0;k<k0+32;k++){
    float wv = W[k]*DC[k];
    float2 xv = xf1[((size_t)b*128+k)*31 + (m+15)];
    acc.x += wv*xv.x; acc.y += wv*xv.y;
  }
  redL[threadIdx.x] = acc;
  __syncthreads();
  if(kc == 0){
    float2 p1 = redL[lp+64], p2 = redL[lp+128], p3 = redL[lp+192];
    acc.x += p1.x + p2.x + p3.x;
    acc.y += p1.y + p2.y + p3.y;
    float s = TWO_PI_F/128.0f;
    FxP[(size_t)c2*16+b] = make_float2(acc.x*s, acc.y*s);
  }
}

// K3: Fy1[c2][o]
__global__ void k_fy1(const float* __restrict__ cst, const float* __restrict__ w1,
                      float2* __restrict__ FyP){
  int idx = blockIdx.x*blockDim.x + threadIdx.x;
  int c2 = idx >> 6, o = idx & 63;
  const float2* psi = (const float2*)(cst + OFF_PSI2) + (size_t)c2*24;
  const float* w1r = w1 + (size_t)o*24;
  float2 acc = make_float2(0.f,0.f);
  for(int g=0;g<24;g++){
    float wv = w1r[g];
    float2 p = psi[g];
    acc.x += wv*p.x; acc.y += wv*p.y;
  }
  FyP[(size_t)c2*64+o] = acc;
}

// K4: fused first conv — exact R14/R16 version (measured best: ~300 us).
__global__ void __launch_bounds__(256,4) k_conv1(const float* __restrict__ cst,
                                                 const float2* __restrict__ FxP,
                                                 const float2* __restrict__ FyP,
                                                 unsigned int* __restrict__ FxB){
  __shared__ __align__(16) char L[39936];
  float2* FxL = (float2*)L;
  float2* FyL = FxL + 256;
  float2* SB  = (float2*)(L + 4096);
  unsigned int* yBu = (unsigned int*)(L + 4096);
  float2* XfB = (float2*)(L + 4096);
  unsigned int* TBu = (unsigned int*)(L + 23936);
  float2* T2B = (float2*)(L + 23936);
  float2* acc2= (float2*)(L + 34176);
  float2* w32 = (float2*)(L + 39616);
  int*    o3T = (int*)(L + 39872);

  int b = blockIdx.x >> 6, o = blockIdx.x & 63;
  int tid = threadIdx.x;
  if(tid < 32){ float ang = (TWO_PI_F/32.0f)*tid; w32[tid] = make_float2(cosf(ang), sinf(ang)); }
  if(tid < 16){ int l = tid; o3T[l] = (4*l*l*l - l)/3; }
  FxL[tid] = FxP[(size_t)tid*16 + b];
  FyL[tid] = FyP[(size_t)tid*64 + o];
  for(int t=tid; t<680; t+=256) acc2[t] = make_float2(0.f,0.f);

  const float* D1A = cst + OFF_D1A;
  const float* D1B = cst + OFF_D1B;

  for(int kt=0; kt<8; kt++){
    int k0 = kt*4;
    __syncthreads();
    for(int t=tid; t<496; t+=256){
      int mi = t/31, niq = t - mi*31;
      int n = niq-15;
      int an = n<0?-n:n;
      int lmin = mi>an?mi:an;
      float2 s0={0,0},s1={0,0},s2={0,0},s3={0,0};
      for(int l=lmin;l<16;l++){
        int c = 2*l+1, l2 = l*l;
        float2 fx = FxL[l2+l+mi];
        float2 fy = FyL[l2+(n+l)];
        float zx = fx.x*fy.x + fx.y*fy.y;
        float zy = fx.y*fy.x - fx.x*fy.y;
        const float4* dp = (const float4*)(D1A + (((size_t)o3T[l] + (mi+l)*c + (n+l))<<5) + k0);
        float4 d0 = dp[0];
        s0.x += d0.x*zx; s0.y += d0.x*zy;
        s1.x += d0.y*zx; s1.y += d0.y*zy;
        s2.x += d0.z*zx; s2.y += d0.z*zy;
        s3.x += d0.w*zx; s3.y += d0.w*zy;
      }
      float2* sp = SB + (size_t)t*5;
      sp[0]=s0; sp[1]=s1; sp[2]=s2; sp[3]=s3;
    }
    __syncthreads();
    {
      int mi = tid >> 4, cp = tid & 15;
      float2 a0[4], a1[4];
      #pragma unroll
      for(int j=0;j<4;j++){ a0[j]=make_float2(0,0); a1[j]=make_float2(0,0); }
      float2 step = w32[cp];
      float2 wv = w32[(15*cp)&31];
      float2 cur = make_float2(wv.x, -wv.y);
      const float2* srow = SB + (size_t)(mi*31)*5;
      for(int nb=0; nb<31; nb++){
        float2 q0 = srow[nb*5+0], q1 = srow[nb*5+1], q2 = srow[nb*5+2], q3 = srow[nb*5+3];
        float px, py;
        bool odd = (nb & 1);
        #define K1STEP(QX,QY,J) \
          px = QX*cur.x - QY*cur.y; py = QX*cur.y + QY*cur.x; \
          a0[J].x += px; a0[J].y += py; \
          if(odd){ a1[J].x += px; a1[J].y += py; } else { a1[J].x -= px; a1[J].y -= py; }
        K1STEP(q0.x,q0.y,0) K1STEP(q1.x,q1.y,1)
        K1STEP(q2.x,q2.y,2) K1STEP(q3.x,q3.y,3)
        #undef K1STEP
        float nx = cur.x*step.x - cur.y*step.y;
        cur.y = cur.x*step.y + cur.y*step.x;
        cur.x = nx;
      }
      unsigned int* tp0 = TBu + (size_t)(mi*32+cp)*5;
      tp0[0]=pk2(a0[0]); tp0[1]=pk2(a0[1]); tp0[2]=pk2(a0[2]); tp0[3]=pk2(a0[3]);
      unsigned int* tp1 = TBu + (size_t)(mi*32+cp+16)*5;
      tp1[0]=pk2(a1[0]); tp1[1]=pk2(a1[1]); tp1[2]=pk2(a1[2]); tp1[3]=pk2(a1[3]);
    }
    __syncthreads();
    {
      int c = tid & 31, aq = tid >> 5;
      float y0[4],y1[4],y2[4],y3[4], t0x[4];
      {
        const unsigned int* t0p = TBu + (size_t)c*5;
        t0x[0]=bflo(t0p[0]); t0x[1]=bflo(t0p[1]); t0x[2]=bflo(t0p[2]); t0x[3]=bflo(t0p[3]);
      }
      #pragma unroll
      for(int j=0;j<4;j++){ y0[j]=0; y1[j]=0; y2[j]=0; y3[j]=0; }
      #pragma unroll
      for(int m=1;m<16;m++){
        float2 w = w32[(m*aq)&31];
        const unsigned int* tp = TBu + (size_t)(m*32+c)*5;
        unsigned int d0=tp[0], d1=tp[1], d2=tp[2], d3=tp[3];
        float tx[4] = {bflo(d0),bflo(d1),bflo(d2),bflo(d3)};
        float ty[4] = {bfhi(d0),bfhi(d1),bfhi(d2),bfhi(d3)};
        #pragma unroll
        for(int j=0;j<4;j++){
          float px = tx[j]*w.x - ty[j]*w.y;
          float py = tx[j]*w.y + ty[j]*w.x;
          y0[j] += px;
          int r = m & 3;
          if(r==0){ y1[j] += px; y3[j] += px; }
          else if(r==1){ y1[j] -= py; y3[j] += py; }
          else if(r==2){ y1[j] -= px; y3[j] -= px; }
          else { y1[j] += py; y3[j] -= py; }
          y2[j] += (m&1)? -px : px;
        }
      }
      #define YWRITE(A, YV) { \
        float v0 = t0x[0]+2.f*YV[0], v1 = t0x[1]+2.f*YV[1], v2 = t0x[2]+2.f*YV[2], v3 = t0x[3]+2.f*YV[3]; \
        v0 = v0>0?v0:0; v1 = v1>0?v1:0; v2 = v2>0?v2:0; v3 = v3>0?v3:0; \
        unsigned int* yp = yBu + ((size_t)(A)*32 + c)*3; \
        yp[0] = f2bf(v0) | (f2bf(v1)<<16); \
        yp[1] = f2bf(v2) | (f2bf(v3)<<16); }
      YWRITE(aq,    y0)
      YWRITE(aq+8,  y1)
      YWRITE(aq+16, y2)
      YWRITE(aq+24, y3)
      #undef YWRITE
    }
    __syncthreads();
    {
      int mp = tid >> 5, c4 = tid & 31;
      float2 t2[4];
      #pragma unroll
      for(int j=0;j<4;j++) t2[j]=make_float2(0,0);
      for(int a=0;a<32;a++){
        float2 w = w32[(mp*a)&31];
        const unsigned int* yp = yBu + ((size_t)a*32 + c4)*3;
        unsigned int d0 = yp[0], d1 = yp[1];
        float yv[4] = {bflo(d0), bfhi(d0), bflo(d1), bfhi(d1)};
        #pragma unroll
        for(int j=0;j<4;j++){
          t2[j].x += yv[j]*w.x;
          t2[j].y -= yv[j]*w.y;
        }
      }
      float2* tp = T2B + (size_t)(mp*32+c4)*5;
      tp[0]=t2[0]; tp[1]=t2[1]; tp[2]=t2[2]; tp[3]=t2[3];
    }
    __syncthreads();
    if(tid < 120){
      int mp = tid/15, npq = tid - mp*15;
      int np = npq-7;
      float2 xf[4];
      #pragma unroll
      for(int j=0;j<4;j++) xf[j]=make_float2(0,0);
      float2 wv = w32[np&31];
      float2 step = make_float2(wv.x, -wv.y);
      float2 cur = make_float2(1.f, 0.f);
      const float2* trow = T2B + (size_t)(mp*32)*5;
      for(int c=0;c<32;c++){
        float2 q0 = trow[c*5+0], q1 = trow[c*5+1], q2 = trow[c*5+2], q3 = trow[c*5+3];
        float tx[4] = {q0.x,q1.x,q2.x,q3.x};
        float ty[4] = {q0.y,q1.y,q2.y,q3.y};
        #pragma unroll
        for(int j=0;j<4;j++){
          xf[j].x += tx[j]*cur.x - ty[j]*cur.y;
          xf[j].y += tx[j]*cur.y + ty[j]*cur.x;
        }
        float nx = cur.x*step.x - cur.y*step.y;
        cur.y = cur.x*step.y + cur.y*step.x;
        cur.x = nx;
      }
      float2* xp = XfB + (size_t)tid*5;
      xp[0]=xf[0]; xp[1]=xf[1]; xp[2]=xf[2]; xp[3]=xf[3];
    }
    __syncthreads();
    if(tid < 225){
      int mi2 = tid/15, ni2 = tid - mi2*15;
      int mp = mi2-7, np = ni2-7;
      float2 xf[4];
      if(mp >= 0){
        const float2* xp = XfB + (size_t)(mp*15+ni2)*5;
        xf[0]=xp[0]; xf[1]=xp[1]; xf[2]=xp[2]; xf[3]=xp[3];
      } else {
        const float2* xp = XfB + (size_t)((-mp)*15+(14-ni2))*5;
        float2 q0=xp[0],q1=xp[1],q2=xp[2],q3=xp[3];
        xf[0]=make_float2(q0.x,-q0.y); xf[1]=make_float2(q1.x,-q1.y);
        xf[2]=make_float2(q2.x,-q2.y); xf[3]=make_float2(q3.x,-q3.y);
      }
      int am = mp<0?-mp:mp, an = np<0?-np:np;
      int lmin = am>an?am:an;
      for(int l=lmin;l<8;l++){
        int c2 = 2*l+1;
        int cidx = o3T[l] + (mp+l)*c2 + (np+l);
        const float4* dp = (const float4*)(D1B + (((size_t)cidx)<<5) + k0);
        float4 d0 = dp[0];
        float rx = d0.x*xf[0].x + d0.y*xf[1].x + d0.z*xf[2].x + d0.w*xf[3].x;
        float ry = d0.x*xf[0].y + d0.y*xf[1].y + d0.z*xf[2].y + d0.w*xf[3].y;
        float2 cur = acc2[cidx];
        cur.x += rx; cur.y += ry;
        acc2[cidx] = cur;
      }
    }
  }
  __syncthreads();
  for(int t=tid; t<680; t+=256){
    float2 v = acc2[t];
    unsigned int pk = f2bf(v.x) | (f2bf(v.y) << 16);
    FxB[(size_t)t*1024 + b*64 + o] = pk;
  }
}

// K5: w2 -> bf16 B-operand layout: wB[io*96 + gpair] packs (g, g+1), io = o*64+i
__global__ void k_w2b(const float* __restrict__ w2, unsigned int* __restrict__ wB){
  int idx = blockIdx.x*256 + threadIdx.x;   // 8192*96
  int io = idx/96, gp = idx - io*96;
  int i = io & 63, o = io >> 6;
  const float* src = w2 + ((size_t)i*128 + o)*192 + gp*2;
  wB[(size_t)io*96 + gp] = f2bf(src[0]) | (f2bf(src[1]) << 16);
}

// K6: Fy2 -> B-hat via bf16 MFMA GEMM. A = psi (const, PSIB table, Re/Im M-rows),
// B = w2 bf16 (wB). Per block: 1 M-tile (16 coefs) x 256 io (4 waves x 4 N-tiles).
// Epilogue writes both B-hat rows (2o: (Br,Bi); 2o+1: (-Bi,Br)) directly.
__global__ void __launch_bounds__(256) k_fy2m(const float* __restrict__ cst,
                                              const unsigned int* __restrict__ wB,
                                              unsigned int* __restrict__ FyB){
  int mt = blockIdx.x >> 5;       // 0..42
  int nb = blockIdx.x & 31;       // 0..31
  int tid = threadIdx.x;
  int lane = tid & 63, wv = tid >> 6;
  int m16 = lane & 15, quad = lane >> 4;
  const unsigned short* PB = (const unsigned short*)(cst + OFF_PSIB);
  bf16x8 aR[6], aI[6];
  #pragma unroll
  for(int ks=0; ks<6; ks++){
    aR[ks] = *(const bf16x8*)(PB + ((((size_t)mt*2+0)*6+ks)*64+lane)*8);
    aI[ks] = *(const bf16x8*)(PB + ((((size_t)mt*2+1)*6+ks)*64+lane)*8);
  }
  const unsigned short* wS = (const unsigned short*)wB;
  int ioW = nb*256 + wv*64;
  #pragma unroll
  for(int t=0; t<4; t++){
    int io = ioW + t*16 + m16;
    const unsigned short* brow = wS + (size_t)io*192 + quad*8;
    f32x4 Dr = {0,0,0,0}, Di = {0,0,0,0};
    #pragma unroll
    for(int ks=0; ks<6; ks++){
      bf16x8 bf = *(const bf16x8*)(brow + ks*32);
      Dr = __builtin_amdgcn_mfma_f32_16x16x32_bf16(aR[ks], bf, Dr, 0,0,0);
      Di = __builtin_amdgcn_mfma_f32_16x16x32_bf16(aI[ks], bf, Di, 0,0,0);
    }
    int o = io >> 6, i = io & 63;
    #pragma unroll
    for(int r=0; r<4; r++){
      int coef = mt*16 + quad*4 + r;
      if(coef < 680){
        size_t base = (size_t)coef*16384;
        FyB[base + (size_t)(2*o  )*64 + i] = f2bf(Dr[r]) | (f2bf(Di[r]) << 16);
        FyB[base + (size_t)(2*o+1)*64 + i] = f2bf(-Di[r]) | (f2bf(Dr[r]) << 16);
      }
    }
  }
}

// K7: Fz2 via bf16 MFMA — Hermitian-halved + 2-way N-split (R16 version).
__global__ void __launch_bounds__(256) k_fz2(const unsigned int* __restrict__ FxB,
                                             const unsigned int* __restrict__ FyB,
                                             float* __restrict__ Fz2f){
  int p = blockIdx.x >> 1, nb = blockIdx.x & 1;
  int c, o3, q;
  if(p < 113)      { c=15; o3=455; q=p; }
  else if(p < 198) { c=13; o3=286; q=p-113; }
  else if(p < 259) { c=11; o3=165; q=p-198; }
  else if(p < 300) { c=9;  o3=84;  q=p-259; }
  else if(p < 325) { c=7;  o3=35;  q=p-300; }
  else if(p < 338) { c=5;  o3=10;  q=p-325; }
  else if(p < 343) { c=3;  o3=1;   q=p-338; }
  else             { c=1;  o3=0;   q=0; }
  int mi = q / c, ni = q - mi*c;
  int lh = c >> 1;

  int tid  = threadIdx.x;
  int lane = tid & 63, wv = tid >> 6;
  int m16  = lane & 15, quad = lane >> 4;

  int nrow = nb*128 + wv*32 + m16;
  int aoff = m16*128 + quad*8;
  int boff = nrow*128 + quad*8;

  f32x4 acc0 = {0,0,0,0}, acc1 = {0,0,0,0};

  const unsigned short* FxS = (const unsigned short*)FxB;
  const unsigned short* FyS = (const unsigned short*)FyB;

  for(int kk=0; kk<c; kk++){
    const unsigned short* Arow = FxS + (size_t)(o3 + mi*c + kk)*2048;
    const unsigned short* Brow = FyS + (size_t)(o3 + ni*c + kk)*32768;
    #pragma unroll
    for(int ig=0; ig<4; ig++){
      bf16x8 af = *(const bf16x8*)(Arow + aoff + ig*32);
      bf16x8 b0 = *(const bf16x8*)(Brow + boff          + ig*32);
      bf16x8 b1 = *(const bf16x8*)(Brow + boff + 2048   + ig*32);
      acc0 = __builtin_amdgcn_mfma_f32_16x16x32_bf16(af, b0, acc0, 0,0,0);
      acc1 = __builtin_amdgcn_mfma_f32_16x16x32_bf16(af, b1, acc1, 0,0,0);
    }
  }
  int coefC = o3 + mi*c + ni;
  float* dst = Fz2f + (size_t)coefC*4096;
  int npb = nrow;
  #pragma unroll
  for(int r=0;r<4;r++){
    int b = quad*4 + r;
    dst[(size_t)b*256 + npb     ] = acc0[r];
    dst[(size_t)b*256 + npb + 16] = acc1[r];
  }
  if(!(mi==lh && ni==lh)){
    int coefM = o3 + (c-1-mi)*c + (c-1-ni);
    float sg = (((mi+ni) + (npb&1)) & 1) ? -1.f : 1.f;
    float* dst2 = Fz2f + (size_t)coefM*4096;
    #pragma unroll
    for(int r=0;r<4;r++){
      int b = quad*4 + r;
      dst2[(size_t)b*256 + npb     ] = sg*acc0[r];
      dst2[(size_t)b*256 + npb + 16] = sg*acc1[r];
    }
  }
}

// K8: slice2 — R14/R16 block version, k-contiguous D2.
__global__ void __launch_bounds__(256) k_slice2(const float* __restrict__ cst,
                                                const float2* __restrict__ Fz2P,
                                                float* __restrict__ featP){
  __shared__ float2 FzL[680];
  __shared__ float2 S2[225];
  __shared__ float2 TA[240];
  __shared__ float2 w16[16];
  __shared__ float red[256];
  int bo = blockIdx.x;
  int tid = threadIdx.x;
  if(tid < 16){ float ang = (TWO_PI_F/16.0f)*tid; w16[tid] = make_float2(cosf(ang), sinf(ang)); }
  for(int t=tid; t<680; t+=256) FzL[t] = Fz2P[(size_t)t*2048 + bo];
  __syncthreads();
  const float* D2  = cst + OFF_D2;
  const float* WL2 = cst + OFF_WL2;
  float part = 0.f;
  for(int k2=0;k2<16;k2++){
    if(tid < 225){
      int mi = tid/15, ni = tid%15;
      int m = mi-7, n = ni-7;
      int am = m<0?-m:m, an = n<0?-n:n;
      int lmin = am>an?am:an;
      float2 acc = make_float2(0.f,0.f);
      for(int l=lmin;l<8;l++){
        int c = 2*l+1;
        int idx = off3d(l) + (m+l)*c + (n+l);
        float dv = D2[((size_t)idx<<4) + k2];
        float2 fzv = FzL[idx];
        acc.x += dv*fzv.x; acc.y += dv*fzv.y;
      }
      S2[tid] = acc;
    }
    __syncthreads();
    if(tid < 240){
      int mi = tid >> 4, c = tid & 15;
      float2 acc = make_float2(0.f,0.f);
      for(int ni=0;ni<15;ni++){
        float2 sv = S2[mi*15+ni];
        float2 w = w16[((ni-7)*c)&15];
        acc.x += sv.x*w.x - sv.y*w.y;
        acc.y += sv.x*w.y + sv.y*w.x;
      }
      TA[mi*16+c] = acc;
    }
    __syncthreads();
    {
      int a = tid >> 4, c = tid & 15;
      float acc = 0.f;
      for(int mi=0;mi<15;mi++){
        float2 tv = TA[mi*16+c];
        float2 w = w16[((mi-7)*a)&15];
        acc += tv.x*w.x - tv.y*w.y;
      }
      if(acc > 0.f) part += WL2[k2]*acc;
    }
    __syncthreads();
  }
  red[tid] = part;
  __syncthreads();
  for(int s=128;s>0;s>>=1){ if(tid<s) red[tid]+=red[tid+s]; __syncthreads(); }
  if(tid==0) featP[bo] = red[0]*(1.0f/256.0f);
}

// K9: out[b,j]
__global__ void k_out(const float* __restrict__ featP, const float* __restrict__ lin_w,
                      const float* __restrict__ lin_b, float* __restrict__ out){
  int t = threadIdx.x;
  if(t < 160){
    int b = t/10, j = t%10;
    float acc = lin_b[j];
    for(int o=0;o<128;o++) acc += featP[b*128+o]*lin_w[j*128+o];
    out[t] = acc;
  }
}

extern "C" void kernel_launch(void* const* d_in, const int* in_sizes, int n_in,
                              void* d_out, int out_size, void* d_ws, size_t ws_size,
                              hipStream_t stream){
  const float* x     = (const float*)d_in[0];
  const float* w1    = (const float*)d_in[1];
  const float* w2    = (const float*)d_in[2];
  const float* lin_w = (const float*)d_in[3];
  const float* lin_b = (const float*)d_in[4];
  float* out = (float*)d_out;
  if(ws_size < WS_NEEDED) return;
  char* ws = (char*)d_ws;
  float2* xf1  = (float2*)(ws + OFS_XF1);
  float2* FxP  = (float2*)(ws + OFS_FX);
  float2* FyP  = (float2*)(ws + OFS_FY1);
  unsigned int* FxB = (unsigned int*)(ws + OFS_FX2);
  unsigned int* FyB = (unsigned int*)(ws + OFS_FY2);
  float2* Fz2P = (float2*)(ws + OFS_FZ2);
  unsigned int* wBP = (unsigned int*)(ws + OFS_W2B);
  float*  featP= (float*)(ws + OFS_FEAT);
  const float* cst = g_const;

  k_fft_alpha<<<2048, 128, 0, stream>>>(x, xf1);
  k_fx      <<<64,   256, 0, stream>>>(cst, xf1, FxP);
  k_fy1     <<<64,   256, 0, stream>>>(cst, w1, FyP);
  k_conv1   <<<1024, 256, 0, stream>>>(cst, FxP, FyP, FxB);
  k_w2b     <<<3072, 256, 0, stream>>>(w2, wBP);
  k_fy2m    <<<1376, 256, 0, stream>>>(cst, wBP, FyB);
  k_fz2     <<<688,  256, 0, stream>>>(FxB, FyB, (float*)Fz2P);
  k_slice2  <<<2048, 256, 0, stream>>>(cst, Fz2P, featP);
  k_out     <<<1,    256, 0, stream>>>(featP, lin_w, lin_b, out);
}